// Round 2
// baseline (1524.111 us; speedup 1.0000x reference)
//
#include <hip/hip_runtime.h>
#include <hip/hip_bf16.h>
#include <cstddef>

#define NB  4
#define QN  900
#define DM  256
#define HH  8
#define HD  32
#define PP  4
#define HBg 200
#define WBg 200
#define FFD 512
#define NV  (HBg*WBg)   // 40000 bev cells

typedef __hip_bfloat16 bf16;

__device__ __forceinline__ float bf2f(bf16 x){ return __bfloat162float(x); }

__device__ __forceinline__ float blk_sum256(float v, float* tmp){
  int t = threadIdx.x;
  tmp[t] = v; __syncthreads();
  for (int s = 128; s > 0; s >>= 1){ if (t < s) tmp[t] += tmp[t+s]; __syncthreads(); }
  float r = tmp[0]; __syncthreads();
  return r;
}
__device__ __forceinline__ float blk_max256(float v, float* tmp){
  int t = threadIdx.x;
  tmp[t] = v; __syncthreads();
  for (int s = 128; s > 0; s >>= 1){ if (t < s) tmp[t] = fmaxf(tmp[t], tmp[t+s]); __syncthreads(); }
  float r = tmp[0]; __syncthreads();
  return r;
}

// ---------------- K1: q/k/v projections (row-per-block, K=256) ----------------
__global__ void proj3_kernel(const float* __restrict__ queries, const float* __restrict__ og,
                             const float* __restrict__ Wq, const float* __restrict__ bq,
                             const float* __restrict__ Wk, const float* __restrict__ bk,
                             const float* __restrict__ Wv, const float* __restrict__ bv,
                             float* __restrict__ qh, float* __restrict__ kh, float* __restrict__ vh){
  int row = blockIdx.x, which = blockIdx.y, t = threadIdx.x;
  __shared__ float a[DM];
  if (which == 2) a[t] = queries[row*DM + t];                       // v input: queries
  else           a[t] = queries[row*DM + t] + og[row*DM + t];       // q,k input: queries+og
  __syncthreads();
  const float* W; const float* b; float* out;
  if (which == 0){ W = Wq; b = bq; out = qh; }
  else if (which == 1){ W = Wk; b = bk; out = kh; }
  else { W = Wv; b = bv; out = vh; }
  float acc = b[t];
  #pragma unroll 8
  for (int k = 0; k < DM; k++) acc += a[k] * W[k*DM + t];
  out[row*DM + t] = acc;
}

// ---------------- K2: MHA, one block per (n,h,q) ----------------
__global__ void mha_kernel(const float* __restrict__ qh, const float* __restrict__ kh,
                           const float* __restrict__ vh, const float* __restrict__ mask,
                           float* __restrict__ attn_out){
  int q = blockIdx.x, h = blockIdx.y, n = blockIdx.z, t = threadIdx.x;
  __shared__ float qv[HD];
  __shared__ float s[QN];
  __shared__ float tmp[256];
  if (t < HD) qv[t] = qh[(n*QN + q)*DM + h*HD + t];
  __syncthreads();
  const float scale = 0.17677669529663687f; // 1/sqrt(32)
  for (int k = t; k < QN; k += 256){
    const float* kr = kh + (n*QN + k)*DM + h*HD;
    float d = 0.f;
    #pragma unroll
    for (int i = 0; i < HD; i++) d += qv[i]*kr[i];
    s[k] = (mask[n*QN + k] > 0.f) ? d*scale : -1e9f;
  }
  __syncthreads();
  float lm = -1e30f;
  for (int k = t; k < QN; k += 256) lm = fmaxf(lm, s[k]);
  float m = blk_max256(lm, tmp);
  float ls = 0.f;
  for (int k = t; k < QN; k += 256){ float e = __expf(s[k] - m); s[k] = e; ls += e; }
  float sum = blk_sum256(ls, tmp);
  float inv = 1.f/sum;
  for (int k = t; k < QN; k += 256) s[k] *= inv;
  __syncthreads();
  int d = t & (HD-1), g = t >> 5;           // 8 groups x 32 dims
  float acc = 0.f;
  for (int k = g; k < QN; k += 8) acc += s[k]*vh[(n*QN + k)*DM + h*HD + d];
  tmp[t] = acc; __syncthreads();
  if (t < HD){
    float o = 0.f;
    #pragma unroll
    for (int gg = 0; gg < 8; gg++) o += tmp[gg*32 + t];
    attn_out[(n*QN + q)*DM + h*HD + t] = o;
  }
}

// ---------------- K3: Wo GEMM + residual + LN1, write out2 and aug ----------------
__global__ void wo_ln_kernel(const float* __restrict__ attn_out,
                             const float* __restrict__ Wo, const float* __restrict__ bo,
                             const float* __restrict__ queries, const float* __restrict__ og,
                             const float* __restrict__ g1, const float* __restrict__ b1,
                             float* __restrict__ out2, float* __restrict__ aug){
  int row = blockIdx.x, t = threadIdx.x;
  __shared__ float a[DM]; __shared__ float tmp[256];
  a[t] = attn_out[row*DM + t]; __syncthreads();
  float acc = bo[t] + queries[row*DM + t];
  #pragma unroll 8
  for (int k = 0; k < DM; k++) acc += a[k]*Wo[k*DM + t];
  float mean = blk_sum256(acc, tmp)*(1.f/DM);
  float c = acc - mean;
  float var = blk_sum256(c*c, tmp)*(1.f/DM);
  float o = c*rsqrtf(var + 1e-5f)*g1[t] + b1[t];
  out2[row*DM + t] = o;
  aug[row*DM + t]  = o + og[row*DM + t];
}

// ---------------- K4: value = bev @ Wval + bval (M-tile 8, bf16 out) ----------------
__global__ void value_gemm_kernel(const float* __restrict__ bev, const float* __restrict__ Wval,
                                  const float* __restrict__ bval, bf16* __restrict__ value){
  int t = threadIdx.x;
  long row0 = (long)blockIdx.x*8;
  __shared__ float a[DM][8];   // [k][r] so a[k][0..7] is contiguous
  for (int idx = t; idx < 8*DM; idx += 256){
    int r = idx >> 8, k = idx & 255;
    a[k][r] = bev[(row0 + r)*DM + k];
  }
  __syncthreads();
  float bias = bval[t];
  float acc[8];
  #pragma unroll
  for (int r = 0; r < 8; r++) acc[r] = bias;
  #pragma unroll 4
  for (int k = 0; k < DM; k++){
    float w = Wval[k*DM + t];
    float4 a0 = *(const float4*)&a[k][0];
    float4 a1 = *(const float4*)&a[k][4];
    acc[0] += a0.x*w; acc[1] += a0.y*w; acc[2] += a0.z*w; acc[3] += a0.w*w;
    acc[4] += a1.x*w; acc[5] += a1.y*w; acc[6] += a1.z*w; acc[7] += a1.w*w;
  }
  #pragma unroll
  for (int r = 0; r < 8; r++) value[(row0 + r)*DM + t] = __float2bfloat16(acc[r]);
}

// ---------------- K5: offsets + attention-weight softmax + sample coords ----------------
__global__ void off_attn_kernel(const float* __restrict__ aug, const float* __restrict__ ref,
                                const float* __restrict__ Woff, const float* __restrict__ boff,
                                const float* __restrict__ Wattn, const float* __restrict__ battn,
                                float* __restrict__ locb, float* __restrict__ awb){
  int row = blockIdx.x, t = threadIdx.x; // 128 threads
  __shared__ float a[DM]; __shared__ float offL[64]; __shared__ float awL[32];
  a[t]       = aug[row*DM + t];
  a[t + 128] = aug[row*DM + t + 128];
  __syncthreads();
  if (t < 64){
    float acc = boff[t];
    for (int k = 0; k < DM; k++) acc += a[k]*Woff[k*64 + t];
    offL[t] = acc;
  } else if (t < 96){
    int j = t - 64;
    float acc = battn[j];
    for (int k = 0; k < DM; k++) acc += a[k]*Wattn[k*32 + j];
    awL[j] = acc;
  }
  __syncthreads();
  if (t < 64){
    int c = t & 1; // 0=x,1=y ; layout j = h*8 + p*2 + c
    float refv = ref[row*2 + c];
    // pixel coords: x = (ref_x + off_x/WB)*WB - 0.5 = ref_x*200 + off_x - 0.5 (same for y, HB=200)
    locb[row*64 + t] = refv*200.0f + offL[t] - 0.5f;
  }
  if (t < 8){
    float m = -1e30f;
    #pragma unroll
    for (int p = 0; p < 4; p++) m = fmaxf(m, awL[t*4 + p]);
    float e[4]; float sm = 0.f;
    #pragma unroll
    for (int p = 0; p < 4; p++){ e[p] = __expf(awL[t*4 + p] - m); sm += e[p]; }
    #pragma unroll
    for (int p = 0; p < 4; p++) awb[row*32 + t*4 + p] = e[p]/sm;
  }
}

// ---------------- K6: bilinear deformable sampling + weight over P ----------------
__global__ void deform_kernel(const bf16* __restrict__ value, const float* __restrict__ locb,
                              const float* __restrict__ awb, float* __restrict__ sampled){
  int row = blockIdx.x, t = threadIdx.x;
  int n = row / QN;
  __shared__ float locS[64]; __shared__ float awS[32];
  if (t < 64) locS[t] = locb[row*64 + t];
  else if (t < 96) awS[t - 64] = awb[row*32 + (t - 64)];
  __syncthreads();
  int h = t >> 5, d = t & 31;
  const bf16* vbase = value + (long)n*NV*DM + h*HD + d;
  float acc = 0.f;
  #pragma unroll
  for (int p = 0; p < PP; p++){
    float x = locS[h*8 + p*2], y = locS[h*8 + p*2 + 1];
    float w = awS[h*4 + p];
    float x0 = floorf(x), y0 = floorf(y);
    float fx = x - x0, fy = y - y0;
    int xi = (int)x0, yi = (int)y0;
    #pragma unroll
    for (int dy = 0; dy < 2; dy++){
      #pragma unroll
      for (int dx = 0; dx < 2; dx++){
        int xc = xi + dx, yc = yi + dy;
        float wg = (dx ? fx : 1.f - fx)*(dy ? fy : 1.f - fy);
        if (xc >= 0 && xc < WBg && yc >= 0 && yc < HBg){
          acc += w*wg*bf2f(vbase[(long)(yc*WBg + xc)*DM]);
        }
      }
    }
  }
  sampled[row*DM + t] = acc;
}

// ---------------- K7: Wdo GEMM + mask + residual + LN2 ----------------
__global__ void wdo_ln_kernel(const float* __restrict__ sampled,
                              const float* __restrict__ Wdo, const float* __restrict__ bdo,
                              const float* __restrict__ mask, const float* __restrict__ out2,
                              const float* __restrict__ g2, const float* __restrict__ b2,
                              float* __restrict__ out4){
  int row = blockIdx.x, t = threadIdx.x;
  __shared__ float a[DM]; __shared__ float tmp[256];
  a[t] = sampled[row*DM + t]; __syncthreads();
  float acc = bdo[t];
  #pragma unroll 8
  for (int k = 0; k < DM; k++) acc += a[k]*Wdo[k*DM + t];
  acc = acc*mask[row] + out2[row*DM + t];
  float mean = blk_sum256(acc, tmp)*(1.f/DM);
  float c = acc - mean;
  float var = blk_sum256(c*c, tmp)*(1.f/DM);
  float o = c*rsqrtf(var + 1e-5f)*g2[t] + b2[t];
  out4[row*DM + t] = o;
}

// ---------------- K8: FFN layer 1 (relu) ----------------
__global__ void ffn1_kernel(const float* __restrict__ out4, const float* __restrict__ W1,
                            const float* __restrict__ b1, float* __restrict__ hid){
  int row = blockIdx.x, t = threadIdx.x;
  __shared__ float a[DM];
  a[t] = out4[row*DM + t]; __syncthreads();
  float acc0 = b1[t], acc1 = b1[t + 256];
  #pragma unroll 8
  for (int k = 0; k < DM; k++){
    float av = a[k];
    acc0 += av*W1[k*FFD + t];
    acc1 += av*W1[k*FFD + t + 256];
  }
  hid[row*FFD + t]       = fmaxf(acc0, 0.f);
  hid[row*FFD + t + 256] = fmaxf(acc1, 0.f);
}

// ---------------- K9: FFN layer 2 + residual + LN3 -> fp32 out ----------------
__global__ void ffn2_ln_kernel(const float* __restrict__ hid, const float* __restrict__ W2,
                               const float* __restrict__ b2, const float* __restrict__ out4,
                               const float* __restrict__ g3, const float* __restrict__ b3,
                               float* __restrict__ out){
  int row = blockIdx.x, t = threadIdx.x;
  __shared__ float a[FFD]; __shared__ float tmp[256];
  a[t]       = hid[row*FFD + t];
  a[t + 256] = hid[row*FFD + t + 256];
  __syncthreads();
  float acc = b2[t] + out4[row*DM + t];
  #pragma unroll 8
  for (int k = 0; k < FFD; k++) acc += a[k]*W2[k*DM + t];
  float mean = blk_sum256(acc, tmp)*(1.f/DM);
  float c = acc - mean;
  float var = blk_sum256(c*c, tmp)*(1.f/DM);
  float o = c*rsqrtf(var + 1e-5f)*g3[t] + b3[t];
  out[row*DM + t] = o;
}

extern "C" void kernel_launch(void* const* d_in, const int* in_sizes, int n_in,
                              void* d_out, int out_size, void* d_ws, size_t ws_size,
                              hipStream_t stream) {
  const float* queries = (const float*)d_in[0];
  const float* bev     = (const float*)d_in[1];
  const float* ref     = (const float*)d_in[2];
  const float* og      = (const float*)d_in[3];
  const float* mask    = (const float*)d_in[4];
  const float* Wq = (const float*)d_in[5];  const float* bq = (const float*)d_in[6];
  const float* Wk = (const float*)d_in[7];  const float* bk = (const float*)d_in[8];
  const float* Wv = (const float*)d_in[9];  const float* bv = (const float*)d_in[10];
  const float* Wo = (const float*)d_in[11]; const float* bo = (const float*)d_in[12];
  const float* ln1g = (const float*)d_in[13]; const float* ln1b = (const float*)d_in[14];
  const float* Wval = (const float*)d_in[15]; const float* bval = (const float*)d_in[16];
  const float* Woff = (const float*)d_in[17]; const float* boff = (const float*)d_in[18];
  const float* Wattn = (const float*)d_in[19]; const float* battn = (const float*)d_in[20];
  const float* Wdo = (const float*)d_in[21]; const float* bdo = (const float*)d_in[22];
  const float* ln2g = (const float*)d_in[23]; const float* ln2b = (const float*)d_in[24];
  const float* W1 = (const float*)d_in[25]; const float* b1 = (const float*)d_in[26];
  const float* W2 = (const float*)d_in[27]; const float* b2 = (const float*)d_in[28];
  const float* ln3g = (const float*)d_in[29]; const float* ln3b = (const float*)d_in[30];

  const int M = NB*QN;            // 3600
  float* ws = (float*)d_ws;
  float* qh       = ws;                   // 921600
  float* kh       = qh + (size_t)M*DM;    // 921600
  float* vh       = kh + (size_t)M*DM;
  float* attn_out = vh + (size_t)M*DM;
  float* out2     = attn_out + (size_t)M*DM;
  float* aug      = out2 + (size_t)M*DM;
  float* out4     = aug + (size_t)M*DM;
  float* sampled  = out4 + (size_t)M*DM;
  float* hid      = sampled + (size_t)M*DM;       // 3600*512
  float* locb     = hid + (size_t)M*FFD;          // 3600*64
  float* awb      = locb + (size_t)M*64;          // 3600*32
  bf16*  value    = (bf16*)(awb + (size_t)M*32);  // 160000*256 bf16

  proj3_kernel<<<dim3(M, 3), 256, 0, stream>>>(queries, og, Wq, bq, Wk, bk, Wv, bv, qh, kh, vh);
  mha_kernel<<<dim3(QN, HH, NB), 256, 0, stream>>>(qh, kh, vh, mask, attn_out);
  wo_ln_kernel<<<M, 256, 0, stream>>>(attn_out, Wo, bo, queries, og, ln1g, ln1b, out2, aug);
  value_gemm_kernel<<<(NB*NV)/8, 256, 0, stream>>>(bev, Wval, bval, value);
  off_attn_kernel<<<M, 128, 0, stream>>>(aug, ref, Woff, boff, Wattn, battn, locb, awb);
  deform_kernel<<<M, 256, 0, stream>>>(value, locb, awb, sampled);
  wdo_ln_kernel<<<M, 256, 0, stream>>>(sampled, Wdo, bdo, mask, out2, ln2g, ln2b, out4);
  ffn1_kernel<<<M, 256, 0, stream>>>(out4, W1, b1, hid);
  ffn2_ln_kernel<<<M, 256, 0, stream>>>(hid, W2, b2, out4, ln3g, ln3b, (float*)d_out);
}

// Round 3
// 1453.309 us; speedup vs baseline: 1.0487x; 1.0487x over previous
//
#include <hip/hip_runtime.h>
#include <hip/hip_bf16.h>
#include <cstddef>

#define NB  4
#define QN  900
#define DM  256
#define HH  8
#define HD  32
#define PP  4
#define HBg 200
#define WBg 200
#define FFD 512
#define NV  (HBg*WBg)   // 40000 bev cells
#define QT  12          // q-tile for mha (75 tiles exactly)

typedef __hip_bfloat16 bf16;

__device__ __forceinline__ float bf2f(bf16 x){ return __bfloat162float(x); }

__device__ __forceinline__ float blk_sum256(float v, float* tmp){
  int t = threadIdx.x;
  tmp[t] = v; __syncthreads();
  for (int s = 128; s > 0; s >>= 1){ if (t < s) tmp[t] += tmp[t+s]; __syncthreads(); }
  float r = tmp[0]; __syncthreads();
  return r;
}

// ---------------- K1: q/k/v projections (row-per-block, K=256) ----------------
// which==1 (K) writes TRANSPOSED: kT[n][h][d][k] so mha score loads coalesce.
__global__ void proj3_kernel(const float* __restrict__ queries, const float* __restrict__ og,
                             const float* __restrict__ Wq, const float* __restrict__ bq,
                             const float* __restrict__ Wk, const float* __restrict__ bk,
                             const float* __restrict__ Wv, const float* __restrict__ bv,
                             float* __restrict__ qh, float* __restrict__ kT, float* __restrict__ vh){
  int row = blockIdx.x, which = blockIdx.y, t = threadIdx.x;
  __shared__ float a[DM];
  if (which == 2) a[t] = queries[row*DM + t];                       // v input: queries
  else           a[t] = queries[row*DM + t] + og[row*DM + t];       // q,k input: queries+og
  __syncthreads();
  const float* W; const float* b;
  if (which == 0){ W = Wq; b = bq; }
  else if (which == 1){ W = Wk; b = bk; }
  else { W = Wv; b = bv; }
  float acc = b[t];
  #pragma unroll 8
  for (int k = 0; k < DM; k++) acc += a[k] * W[k*DM + t];
  if (which == 1){
    int n = row / QN, q = row - n*QN;
    int h = t >> 5, i = t & 31;
    kT[(((n*HH + h)*HD) + i)*QN + q] = acc;
  } else if (which == 0){
    qh[row*DM + t] = acc;
  } else {
    vh[row*DM + t] = acc;
  }
}

// ---------------- K2: MHA, Q-tiled two-pass; block per (qtile,h,n) ----------------
__global__ void mha_kernel(const float* __restrict__ qh, const float* __restrict__ kT,
                           const float* __restrict__ vh, const float* __restrict__ mask,
                           float* __restrict__ attn_out){
  int qt = blockIdx.x, h = blockIdx.y, n = blockIdx.z, t = threadIdx.x;
  int q0 = qt*QT;
  __shared__ float qS[QT][HD];
  __shared__ float sS[QT][QN];
  // load Q tile
  for (int idx = t; idx < QT*HD; idx += 256){
    int qi = idx >> 5, i = idx & 31;
    qS[qi][i] = qh[(n*QN + q0 + qi)*DM + h*HD + i];
  }
  __syncthreads();
  const float scale = 0.17677669529663687f; // 1/sqrt(32)
  // phase 1: scores, coalesced kT loads, 12 FMA per load
  const float* kbase = kT + (size_t)((n*HH + h)*HD)*QN;
  for (int k = t; k < QN; k += 256){
    float sc[QT];
    #pragma unroll
    for (int qi = 0; qi < QT; qi++) sc[qi] = 0.f;
    #pragma unroll 8
    for (int i = 0; i < HD; i++){
      float kv = kbase[i*QN + k];
      #pragma unroll
      for (int qi = 0; qi < QT; qi++) sc[qi] += qS[qi][i]*kv;
    }
    bool keep = mask[n*QN + k] > 0.f;
    #pragma unroll
    for (int qi = 0; qi < QT; qi++) sS[qi][k] = keep ? sc[qi]*scale : -1e9f;
  }
  __syncthreads();
  // phase 2: softmax per row, one wave handles 3 rows
  int wv = t >> 6, ln = t & 63;
  for (int r = wv*3; r < wv*3 + 3; r++){
    float m = -1e30f;
    for (int k = ln; k < QN; k += 64) m = fmaxf(m, sS[r][k]);
    #pragma unroll
    for (int off = 32; off; off >>= 1) m = fmaxf(m, __shfl_xor(m, off));
    float sum = 0.f;
    for (int k = ln; k < QN; k += 64){ float e = __expf(sS[r][k] - m); sS[r][k] = e; sum += e; }
    #pragma unroll
    for (int off = 32; off; off >>= 1) sum += __shfl_xor(sum, off);
    float inv = 1.f/sum;
    for (int k = ln; k < QN; k += 64) sS[r][k] *= inv;
  }
  __syncthreads();
  // phase 3: PV. thread = (d, group); groups 0..7 own row g, groups 0..3 also row g+8
  int d = t & 31, g = t >> 5;
  int r0 = g, r1 = g + 8;
  float a0 = 0.f, a1 = 0.f;
  const float* vp = vh + (size_t)(n*QN)*DM + h*HD + d;
  #pragma unroll 4
  for (int k = 0; k < QN; k++){
    float v = vp[(size_t)k*DM];
    a0 += sS[r0][k]*v;
    if (g < 4) a1 += sS[r1][k]*v;   // wave-uniform branch
  }
  attn_out[(size_t)(n*QN + q0 + r0)*DM + h*HD + d] = a0;
  if (g < 4) attn_out[(size_t)(n*QN + q0 + r1)*DM + h*HD + d] = a1;
}

// ---------------- K3: Wo GEMM + residual + LN1, write out2 and aug ----------------
__global__ void wo_ln_kernel(const float* __restrict__ attn_out,
                             const float* __restrict__ Wo, const float* __restrict__ bo,
                             const float* __restrict__ queries, const float* __restrict__ og,
                             const float* __restrict__ g1, const float* __restrict__ b1,
                             float* __restrict__ out2, float* __restrict__ aug){
  int row = blockIdx.x, t = threadIdx.x;
  __shared__ float a[DM]; __shared__ float tmp[256];
  a[t] = attn_out[row*DM + t]; __syncthreads();
  float acc = bo[t] + queries[row*DM + t];
  #pragma unroll 8
  for (int k = 0; k < DM; k++) acc += a[k]*Wo[k*DM + t];
  float mean = blk_sum256(acc, tmp)*(1.f/DM);
  float c = acc - mean;
  float var = blk_sum256(c*c, tmp)*(1.f/DM);
  float o = c*rsqrtf(var + 1e-5f)*g1[t] + b1[t];
  out2[row*DM + t] = o;
  aug[row*DM + t]  = o + og[row*DM + t];
}

// ---------------- K4: value = bev @ Wval + bval (M-tile 8, bf16 out) ----------------
__global__ void value_gemm_kernel(const float* __restrict__ bev, const float* __restrict__ Wval,
                                  const float* __restrict__ bval, bf16* __restrict__ value){
  int t = threadIdx.x;
  long row0 = (long)blockIdx.x*8;
  __shared__ float a[DM][8];   // [k][r] so a[k][0..7] is contiguous
  for (int idx = t; idx < 8*DM; idx += 256){
    int r = idx >> 8, k = idx & 255;
    a[k][r] = bev[(row0 + r)*DM + k];
  }
  __syncthreads();
  float bias = bval[t];
  float acc[8];
  #pragma unroll
  for (int r = 0; r < 8; r++) acc[r] = bias;
  #pragma unroll 4
  for (int k = 0; k < DM; k++){
    float w = Wval[k*DM + t];
    float4 a0 = *(const float4*)&a[k][0];
    float4 a1 = *(const float4*)&a[k][4];
    acc[0] += a0.x*w; acc[1] += a0.y*w; acc[2] += a0.z*w; acc[3] += a0.w*w;
    acc[4] += a1.x*w; acc[5] += a1.y*w; acc[6] += a1.z*w; acc[7] += a1.w*w;
  }
  #pragma unroll
  for (int r = 0; r < 8; r++) value[(row0 + r)*DM + t] = __float2bfloat16(acc[r]);
}

// ---------------- K5: offsets + attention-weight softmax + sample coords ----------------
__global__ void off_attn_kernel(const float* __restrict__ aug, const float* __restrict__ ref,
                                const float* __restrict__ Woff, const float* __restrict__ boff,
                                const float* __restrict__ Wattn, const float* __restrict__ battn,
                                float* __restrict__ locb, float* __restrict__ awb){
  int row = blockIdx.x, t = threadIdx.x; // 128 threads
  __shared__ float a[DM]; __shared__ float offL[64]; __shared__ float awL[32];
  a[t]       = aug[row*DM + t];
  a[t + 128] = aug[row*DM + t + 128];
  __syncthreads();
  if (t < 64){
    float acc = boff[t];
    for (int k = 0; k < DM; k++) acc += a[k]*Woff[k*64 + t];
    offL[t] = acc;
  } else if (t < 96){
    int j = t - 64;
    float acc = battn[j];
    for (int k = 0; k < DM; k++) acc += a[k]*Wattn[k*32 + j];
    awL[j] = acc;
  }
  __syncthreads();
  if (t < 64){
    int c = t & 1; // 0=x,1=y ; layout j = h*8 + p*2 + c
    float refv = ref[row*2 + c];
    locb[row*64 + t] = refv*200.0f + offL[t] - 0.5f;
  }
  if (t < 8){
    float m = -1e30f;
    #pragma unroll
    for (int p = 0; p < 4; p++) m = fmaxf(m, awL[t*4 + p]);
    float e[4]; float sm = 0.f;
    #pragma unroll
    for (int p = 0; p < 4; p++){ e[p] = __expf(awL[t*4 + p] - m); sm += e[p]; }
    #pragma unroll
    for (int p = 0; p < 4; p++) awb[row*32 + t*4 + p] = e[p]/sm;
  }
}

// ---------------- K6: bilinear deformable sampling + weight over P ----------------
__global__ void deform_kernel(const bf16* __restrict__ value, const float* __restrict__ locb,
                              const float* __restrict__ awb, float* __restrict__ sampled){
  int row = blockIdx.x, t = threadIdx.x;
  int n = row / QN;
  __shared__ float locS[64]; __shared__ float awS[32];
  if (t < 64) locS[t] = locb[row*64 + t];
  else if (t < 96) awS[t - 64] = awb[row*32 + (t - 64)];
  __syncthreads();
  int h = t >> 5, d = t & 31;
  const bf16* vbase = value + (long)n*NV*DM + h*HD + d;
  float acc = 0.f;
  #pragma unroll
  for (int p = 0; p < PP; p++){
    float x = locS[h*8 + p*2], y = locS[h*8 + p*2 + 1];
    float w = awS[h*4 + p];
    float x0 = floorf(x), y0 = floorf(y);
    float fx = x - x0, fy = y - y0;
    int xi = (int)x0, yi = (int)y0;
    #pragma unroll
    for (int dy = 0; dy < 2; dy++){
      #pragma unroll
      for (int dx = 0; dx < 2; dx++){
        int xc = xi + dx, yc = yi + dy;
        float wg = (dx ? fx : 1.f - fx)*(dy ? fy : 1.f - fy);
        if (xc >= 0 && xc < WBg && yc >= 0 && yc < HBg){
          acc += w*wg*bf2f(vbase[(long)(yc*WBg + xc)*DM]);
        }
      }
    }
  }
  sampled[row*DM + t] = acc;
}

// ---------------- K7: Wdo GEMM + mask + residual + LN2 ----------------
__global__ void wdo_ln_kernel(const float* __restrict__ sampled,
                              const float* __restrict__ Wdo, const float* __restrict__ bdo,
                              const float* __restrict__ mask, const float* __restrict__ out2,
                              const float* __restrict__ g2, const float* __restrict__ b2,
                              float* __restrict__ out4){
  int row = blockIdx.x, t = threadIdx.x;
  __shared__ float a[DM]; __shared__ float tmp[256];
  a[t] = sampled[row*DM + t]; __syncthreads();
  float acc = bdo[t];
  #pragma unroll 8
  for (int k = 0; k < DM; k++) acc += a[k]*Wdo[k*DM + t];
  acc = acc*mask[row] + out2[row*DM + t];
  float mean = blk_sum256(acc, tmp)*(1.f/DM);
  float c = acc - mean;
  float var = blk_sum256(c*c, tmp)*(1.f/DM);
  float o = c*rsqrtf(var + 1e-5f)*g2[t] + b2[t];
  out4[row*DM + t] = o;
}

// ---------------- K8: FFN layer 1 (relu) ----------------
__global__ void ffn1_kernel(const float* __restrict__ out4, const float* __restrict__ W1,
                            const float* __restrict__ b1, float* __restrict__ hid){
  int row = blockIdx.x, t = threadIdx.x;
  __shared__ float a[DM];
  a[t] = out4[row*DM + t]; __syncthreads();
  float acc0 = b1[t], acc1 = b1[t + 256];
  #pragma unroll 8
  for (int k = 0; k < DM; k++){
    float av = a[k];
    acc0 += av*W1[k*FFD + t];
    acc1 += av*W1[k*FFD + t + 256];
  }
  hid[row*FFD + t]       = fmaxf(acc0, 0.f);
  hid[row*FFD + t + 256] = fmaxf(acc1, 0.f);
}

// ---------------- K9: FFN layer 2 + residual + LN3 -> fp32 out ----------------
__global__ void ffn2_ln_kernel(const float* __restrict__ hid, const float* __restrict__ W2,
                               const float* __restrict__ b2, const float* __restrict__ out4,
                               const float* __restrict__ g3, const float* __restrict__ b3,
                               float* __restrict__ out){
  int row = blockIdx.x, t = threadIdx.x;
  __shared__ float a[FFD]; __shared__ float tmp[256];
  a[t]       = hid[row*FFD + t];
  a[t + 256] = hid[row*FFD + t + 256];
  __syncthreads();
  float acc = b2[t] + out4[row*DM + t];
  #pragma unroll 8
  for (int k = 0; k < FFD; k++) acc += a[k]*W2[k*DM + t];
  float mean = blk_sum256(acc, tmp)*(1.f/DM);
  float c = acc - mean;
  float var = blk_sum256(c*c, tmp)*(1.f/DM);
  float o = c*rsqrtf(var + 1e-5f)*g3[t] + b3[t];
  out[row*DM + t] = o;
}

extern "C" void kernel_launch(void* const* d_in, const int* in_sizes, int n_in,
                              void* d_out, int out_size, void* d_ws, size_t ws_size,
                              hipStream_t stream) {
  const float* queries = (const float*)d_in[0];
  const float* bev     = (const float*)d_in[1];
  const float* ref     = (const float*)d_in[2];
  const float* og      = (const float*)d_in[3];
  const float* mask    = (const float*)d_in[4];
  const float* Wq = (const float*)d_in[5];  const float* bq = (const float*)d_in[6];
  const float* Wk = (const float*)d_in[7];  const float* bk = (const float*)d_in[8];
  const float* Wv = (const float*)d_in[9];  const float* bv = (const float*)d_in[10];
  const float* Wo = (const float*)d_in[11]; const float* bo = (const float*)d_in[12];
  const float* ln1g = (const float*)d_in[13]; const float* ln1b = (const float*)d_in[14];
  const float* Wval = (const float*)d_in[15]; const float* bval = (const float*)d_in[16];
  const float* Woff = (const float*)d_in[17]; const float* boff = (const float*)d_in[18];
  const float* Wattn = (const float*)d_in[19]; const float* battn = (const float*)d_in[20];
  const float* Wdo = (const float*)d_in[21]; const float* bdo = (const float*)d_in[22];
  const float* ln2g = (const float*)d_in[23]; const float* ln2b = (const float*)d_in[24];
  const float* W1 = (const float*)d_in[25]; const float* b1 = (const float*)d_in[26];
  const float* W2 = (const float*)d_in[27]; const float* b2 = (const float*)d_in[28];
  const float* ln3g = (const float*)d_in[29]; const float* ln3b = (const float*)d_in[30];

  const int M = NB*QN;            // 3600
  float* ws = (float*)d_ws;
  float* qh       = ws;                   // 921600
  float* kT       = qh + (size_t)M*DM;    // 921600  [n][h][d][k]
  float* vh       = kT + (size_t)M*DM;
  float* attn_out = vh + (size_t)M*DM;
  float* out2     = attn_out + (size_t)M*DM;
  float* aug      = out2 + (size_t)M*DM;
  float* out4     = aug + (size_t)M*DM;
  float* sampled  = out4 + (size_t)M*DM;
  float* hid      = sampled + (size_t)M*DM;       // 3600*512
  float* locb     = hid + (size_t)M*FFD;          // 3600*64
  float* awb      = locb + (size_t)M*64;          // 3600*32
  bf16*  value    = (bf16*)(awb + (size_t)M*32);  // 160000*256 bf16

  proj3_kernel<<<dim3(M, 3), 256, 0, stream>>>(queries, og, Wq, bq, Wk, bk, Wv, bv, qh, kT, vh);
  mha_kernel<<<dim3(QN/QT, HH, NB), 256, 0, stream>>>(qh, kT, vh, mask, attn_out);
  wo_ln_kernel<<<M, 256, 0, stream>>>(attn_out, Wo, bo, queries, og, ln1g, ln1b, out2, aug);
  value_gemm_kernel<<<(NB*NV)/8, 256, 0, stream>>>(bev, Wval, bval, value);
  off_attn_kernel<<<M, 128, 0, stream>>>(aug, ref, Woff, boff, Wattn, battn, locb, awb);
  deform_kernel<<<M, 256, 0, stream>>>(value, locb, awb, sampled);
  wdo_ln_kernel<<<M, 256, 0, stream>>>(sampled, Wdo, bdo, mask, out2, ln2g, ln2b, out4);
  ffn1_kernel<<<M, 256, 0, stream>>>(out4, W1, b1, hid);
  ffn2_ln_kernel<<<M, 256, 0, stream>>>(hid, W2, b2, out4, ln3g, ln3b, (float*)d_out);
}

// Round 4
// 863.411 us; speedup vs baseline: 1.7652x; 1.6832x over previous
//
#include <hip/hip_runtime.h>
#include <hip/hip_bf16.h>
#include <cstddef>

#define NB  4
#define QN  900
#define DM  256
#define HH  8
#define HD  32
#define PP  4
#define HBg 200
#define WBg 200
#define FFD 512
#define NV  (HBg*WBg)   // 40000 bev cells
#define QT  6           // q-tile for mha (150 tiles exactly)

typedef __hip_bfloat16 bf16;
typedef __attribute__((ext_vector_type(8))) short short8;
typedef __attribute__((ext_vector_type(4))) float floatx4;

__device__ __forceinline__ float bf2f(bf16 x){ return __bfloat162float(x); }
__device__ __forceinline__ unsigned short f2bu(float f){
  bf16 h = __float2bfloat16(f);
  return *(unsigned short*)&h;
}

__device__ __forceinline__ float blk_sum256(float v, float* tmp){
  int t = threadIdx.x;
  tmp[t] = v; __syncthreads();
  for (int s = 128; s > 0; s >>= 1){ if (t < s) tmp[t] += tmp[t+s]; __syncthreads(); }
  float r = tmp[0]; __syncthreads();
  return r;
}

// ---------------- K1: q/k/v projections, 8 rows per block ----------------
// which==1 (K) writes TRANSPOSED: kT[n][h][d][k] so mha score loads coalesce.
__global__ void proj3_kernel(const float* __restrict__ queries, const float* __restrict__ og,
                             const float* __restrict__ Wq, const float* __restrict__ bq,
                             const float* __restrict__ Wk, const float* __restrict__ bk,
                             const float* __restrict__ Wv, const float* __restrict__ bv,
                             float* __restrict__ qh, float* __restrict__ kT, float* __restrict__ vh){
  int which = blockIdx.y, t = threadIdx.x;
  int row0 = blockIdx.x*8;
  __shared__ float aS[DM][9];   // [k][r], pad 8->9 breaks bank alignment
  for (int idx = t; idx < 8*DM; idx += 256){
    int r = idx >> 8, k = idx & 255;
    float v = queries[(size_t)(row0 + r)*DM + k];
    if (which != 2) v += og[(size_t)(row0 + r)*DM + k];
    aS[k][r] = v;
  }
  __syncthreads();
  const float* W; const float* b;
  if (which == 0){ W = Wq; b = bq; }
  else if (which == 1){ W = Wk; b = bk; }
  else { W = Wv; b = bv; }
  float bias = b[t];
  float acc[8];
  #pragma unroll
  for (int r = 0; r < 8; r++) acc[r] = bias;
  #pragma unroll 4
  for (int k = 0; k < DM; k++){
    float w = W[k*DM + t];
    floatx4 a0 = *(floatx4*)&aS[k][0];
    floatx4 a1 = *(floatx4*)&aS[k][4];
    acc[0] += a0.x*w; acc[1] += a0.y*w; acc[2] += a0.z*w; acc[3] += a0.w*w;
    acc[4] += a1.x*w; acc[5] += a1.y*w; acc[6] += a1.z*w; acc[7] += a1.w*w;
  }
  if (which == 1){
    int h = t >> 5, i = t & 31;
    #pragma unroll
    for (int r = 0; r < 8; r++){
      int row = row0 + r, n = row / QN, q = row - n*QN;
      kT[(size_t)(((n*HH + h)*HD) + i)*QN + q] = acc[r];
    }
  } else {
    float* out = (which == 0) ? qh : vh;
    #pragma unroll
    for (int r = 0; r < 8; r++) out[(size_t)(row0 + r)*DM + t] = acc[r];
  }
}

// ---------------- K2: MHA, Q-tiled two-pass; block per (qtile,h,n) ----------------
__global__ void mha_kernel(const float* __restrict__ qh, const float* __restrict__ kT,
                           const float* __restrict__ vh, const float* __restrict__ mask,
                           float* __restrict__ attn_out){
  int qt = blockIdx.x, h = blockIdx.y, n = blockIdx.z, t = threadIdx.x;
  int q0 = qt*QT;
  __shared__ float qS[QT][HD];
  __shared__ float sS[QT][QN];
  __shared__ float pS[8][QT][HD];
  if (t < QT*HD){
    int qi = t >> 5, i = t & 31;
    qS[qi][i] = qh[(size_t)(n*QN + q0 + qi)*DM + h*HD + i];
  }
  __syncthreads();
  const float scale = 0.17677669529663687f; // 1/sqrt(32)
  // phase 1: scores, coalesced kT loads, QT FMA per load
  const float* kbase = kT + (size_t)((n*HH + h)*HD)*QN;
  for (int k = t; k < QN; k += 256){
    float sc[QT];
    #pragma unroll
    for (int qi = 0; qi < QT; qi++) sc[qi] = 0.f;
    #pragma unroll 8
    for (int i = 0; i < HD; i++){
      float kv = kbase[i*QN + k];
      #pragma unroll
      for (int qi = 0; qi < QT; qi++) sc[qi] += qS[qi][i]*kv;
    }
    bool keep = mask[n*QN + k] > 0.f;
    #pragma unroll
    for (int qi = 0; qi < QT; qi++) sS[qi][k] = keep ? sc[qi]*scale : -1e9f;
  }
  __syncthreads();
  // phase 2: softmax per row, wave-strided rows
  int wv = t >> 6, ln = t & 63;
  for (int r = wv; r < QT; r += 4){
    float m = -1e30f;
    for (int k = ln; k < QN; k += 64) m = fmaxf(m, sS[r][k]);
    #pragma unroll
    for (int off = 32; off; off >>= 1) m = fmaxf(m, __shfl_xor(m, off));
    float sum = 0.f;
    for (int k = ln; k < QN; k += 64){ float e = __expf(sS[r][k] - m); sS[r][k] = e; sum += e; }
    #pragma unroll
    for (int off = 32; off; off >>= 1) sum += __shfl_xor(sum, off);
    float inv = 1.f/sum;
    for (int k = ln; k < QN; k += 64) sS[r][k] *= inv;
  }
  __syncthreads();
  // phase 3: PV with 8-way k-split: thread = (j = t>>5, d = t&31)
  int j = t >> 5, d = t & 31;
  const float* vp = vh + (size_t)(n*QN)*DM + h*HD + d;
  float acc[QT];
  #pragma unroll
  for (int r = 0; r < QT; r++) acc[r] = 0.f;
  for (int k = j; k < QN; k += 8){
    float v = vp[(size_t)k*DM];
    #pragma unroll
    for (int r = 0; r < QT; r++) acc[r] += sS[r][k]*v;
  }
  #pragma unroll
  for (int r = 0; r < QT; r++) pS[j][r][d] = acc[r];
  __syncthreads();
  if (t < QT*HD){
    int r = t >> 5, dd = t & 31;
    float o = 0.f;
    #pragma unroll
    for (int jj = 0; jj < 8; jj++) o += pS[jj][r][dd];
    attn_out[(size_t)(n*QN + q0 + r)*DM + h*HD + dd] = o;
  }
}

// ---------------- K3: Wo GEMM + residual + LN1, write out2 and aug ----------------
__global__ void wo_ln_kernel(const float* __restrict__ attn_out,
                             const float* __restrict__ Wo, const float* __restrict__ bo,
                             const float* __restrict__ queries, const float* __restrict__ og,
                             const float* __restrict__ g1, const float* __restrict__ b1,
                             float* __restrict__ out2, float* __restrict__ aug){
  int row = blockIdx.x, t = threadIdx.x;
  __shared__ float a[DM]; __shared__ float tmp[256];
  a[t] = attn_out[row*DM + t]; __syncthreads();
  float acc = bo[t] + queries[row*DM + t];
  #pragma unroll 8
  for (int k = 0; k < DM; k++) acc += a[k]*Wo[k*DM + t];
  float mean = blk_sum256(acc, tmp)*(1.f/DM);
  float c = acc - mean;
  float var = blk_sum256(c*c, tmp)*(1.f/DM);
  float o = c*rsqrtf(var + 1e-5f)*g1[t] + b1[t];
  out2[row*DM + t] = o;
  aug[row*DM + t]  = o + og[row*DM + t];
}

// ---------------- K4: value = bev @ Wval + bval, bf16 MFMA 64x64 tile ----------------
__global__ void value_gemm_mfma(const float* __restrict__ bev, const float* __restrict__ Wval,
                                const float* __restrict__ bval, bf16* __restrict__ value){
  int t = threadIdx.x;
  int l = t & 63, w = t >> 6;          // lane, wave
  int wm = w >> 1, wn = w & 1;         // wave tile coords (2x2 waves, 32x32 each)
  long row0 = (long)blockIdx.x*64;
  int n0 = blockIdx.y*64;
  __shared__ __align__(16) short As[64*40];  // [r][k] bf16, stride 40 (pad)
  __shared__ __align__(16) short Bs[64*40];  // [n][k] bf16 (B transposed), stride 40

  floatx4 acc[2][2];
  #pragma unroll
  for (int tm = 0; tm < 2; tm++)
    #pragma unroll
    for (int tn = 0; tn < 2; tn++){
      float b = bval[n0 + wn*32 + tn*16 + (l & 15)];
      acc[tm][tn] = (floatx4){b, b, b, b};
    }

  for (int kt = 0; kt < 8; kt++){
    int k0 = kt*32;
    // stage A: 64 rows x 32 k, as float2 -> packed bf16x2
    #pragma unroll
    for (int i = 0; i < 4; i++){
      int p = t + i*256;            // 0..1023
      int r = p >> 4, c2 = p & 15;  // k = c2*2
      const float2* ap = (const float2*)(bev + (size_t)(row0 + r)*DM + k0);
      float2 v = ap[c2];
      unsigned int pk = (unsigned int)f2bu(v.x) | ((unsigned int)f2bu(v.y) << 16);
      *(unsigned int*)&As[r*40 + c2*2] = pk;
    }
    // stage B: 32 k x 64 n -> Bs[n][k]
    #pragma unroll
    for (int i = 0; i < 4; i++){
      int p = t + i*256;            // 0..1023
      int k = p >> 5, n2 = p & 31;  // n = n2*2
      const float2* bp = (const float2*)(Wval + (size_t)(k0 + k)*DM + n0);
      float2 v = bp[n2];
      Bs[(n2*2)*40 + k]     = (short)f2bu(v.x);
      Bs[(n2*2 + 1)*40 + k] = (short)f2bu(v.y);
    }
    __syncthreads();
    short8 af[2], bfr[2];
    #pragma unroll
    for (int tm = 0; tm < 2; tm++)
      af[tm] = *(short8*)&As[(wm*32 + tm*16 + (l & 15))*40 + (l >> 4)*8];
    #pragma unroll
    for (int tn = 0; tn < 2; tn++)
      bfr[tn] = *(short8*)&Bs[(wn*32 + tn*16 + (l & 15))*40 + (l >> 4)*8];
    #pragma unroll
    for (int tm = 0; tm < 2; tm++)
      #pragma unroll
      for (int tn = 0; tn < 2; tn++)
        acc[tm][tn] = __builtin_amdgcn_mfma_f32_16x16x32_bf16(af[tm], bfr[tn], acc[tm][tn], 0, 0, 0);
    __syncthreads();
  }
  // C/D layout: col = lane&15, row = (lane>>4)*4 + reg
  #pragma unroll
  for (int tm = 0; tm < 2; tm++)
    #pragma unroll
    for (int tn = 0; tn < 2; tn++){
      long grow = row0 + wm*32 + tm*16 + (l >> 4)*4;
      int gcol = n0 + wn*32 + tn*16 + (l & 15);
      #pragma unroll
      for (int r = 0; r < 4; r++)
        value[(grow + r)*DM + gcol] = __float2bfloat16(acc[tm][tn][r]);
    }
}

// ---------------- K5: offsets + attention-weight softmax + sample coords ----------------
__global__ void off_attn_kernel(const float* __restrict__ aug, const float* __restrict__ ref,
                                const float* __restrict__ Woff, const float* __restrict__ boff,
                                const float* __restrict__ Wattn, const float* __restrict__ battn,
                                float* __restrict__ locb, float* __restrict__ awb){
  int row = blockIdx.x, t = threadIdx.x; // 128 threads
  __shared__ float a[DM]; __shared__ float offL[64]; __shared__ float awL[32];
  a[t]       = aug[row*DM + t];
  a[t + 128] = aug[row*DM + t + 128];
  __syncthreads();
  if (t < 64){
    float acc = boff[t];
    for (int k = 0; k < DM; k++) acc += a[k]*Woff[k*64 + t];
    offL[t] = acc;
  } else if (t < 96){
    int j = t - 64;
    float acc = battn[j];
    for (int k = 0; k < DM; k++) acc += a[k]*Wattn[k*32 + j];
    awL[j] = acc;
  }
  __syncthreads();
  if (t < 64){
    int c = t & 1; // 0=x,1=y ; layout j = h*8 + p*2 + c
    float refv = ref[row*2 + c];
    locb[row*64 + t] = refv*200.0f + offL[t] - 0.5f;
  }
  if (t < 8){
    float m = -1e30f;
    #pragma unroll
    for (int p = 0; p < 4; p++) m = fmaxf(m, awL[t*4 + p]);
    float e[4]; float sm = 0.f;
    #pragma unroll
    for (int p = 0; p < 4; p++){ e[p] = __expf(awL[t*4 + p] - m); sm += e[p]; }
    #pragma unroll
    for (int p = 0; p < 4; p++) awb[row*32 + t*4 + p] = e[p]/sm;
  }
}

// ---------------- K6: bilinear deformable sampling + weight over P ----------------
__global__ void deform_kernel(const bf16* __restrict__ value, const float* __restrict__ locb,
                              const float* __restrict__ awb, float* __restrict__ sampled){
  int row = blockIdx.x, t = threadIdx.x;
  int n = row / QN;
  __shared__ float locS[64]; __shared__ float awS[32];
  if (t < 64) locS[t] = locb[row*64 + t];
  else if (t < 96) awS[t - 64] = awb[row*32 + (t - 64)];
  __syncthreads();
  int h = t >> 5, d = t & 31;
  const bf16* vbase = value + (long)n*NV*DM + h*HD + d;
  float acc = 0.f;
  #pragma unroll
  for (int p = 0; p < PP; p++){
    float x = locS[h*8 + p*2], y = locS[h*8 + p*2 + 1];
    float w = awS[h*4 + p];
    float x0 = floorf(x), y0 = floorf(y);
    float fx = x - x0, fy = y - y0;
    int xi = (int)x0, yi = (int)y0;
    #pragma unroll
    for (int dy = 0; dy < 2; dy++){
      #pragma unroll
      for (int dx = 0; dx < 2; dx++){
        int xc = xi + dx, yc = yi + dy;
        float wg = (dx ? fx : 1.f - fx)*(dy ? fy : 1.f - fy);
        if (xc >= 0 && xc < WBg && yc >= 0 && yc < HBg){
          acc += w*wg*bf2f(vbase[(long)(yc*WBg + xc)*DM]);
        }
      }
    }
  }
  sampled[row*DM + t] = acc;
}

// ---------------- K7: Wdo GEMM + mask + residual + LN2 ----------------
__global__ void wdo_ln_kernel(const float* __restrict__ sampled,
                              const float* __restrict__ Wdo, const float* __restrict__ bdo,
                              const float* __restrict__ mask, const float* __restrict__ out2,
                              const float* __restrict__ g2, const float* __restrict__ b2,
                              float* __restrict__ out4){
  int row = blockIdx.x, t = threadIdx.x;
  __shared__ float a[DM]; __shared__ float tmp[256];
  a[t] = sampled[row*DM + t]; __syncthreads();
  float acc = bdo[t];
  #pragma unroll 8
  for (int k = 0; k < DM; k++) acc += a[k]*Wdo[k*DM + t];
  acc = acc*mask[row] + out2[row*DM + t];
  float mean = blk_sum256(acc, tmp)*(1.f/DM);
  float c = acc - mean;
  float var = blk_sum256(c*c, tmp)*(1.f/DM);
  float o = c*rsqrtf(var + 1e-5f)*g2[t] + b2[t];
  out4[row*DM + t] = o;
}

// ---------------- K8: FFN layer 1 (relu) ----------------
__global__ void ffn1_kernel(const float* __restrict__ out4, const float* __restrict__ W1,
                            const float* __restrict__ b1, float* __restrict__ hid){
  int row = blockIdx.x, t = threadIdx.x;
  __shared__ float a[DM];
  a[t] = out4[row*DM + t]; __syncthreads();
  float acc0 = b1[t], acc1 = b1[t + 256];
  #pragma unroll 8
  for (int k = 0; k < DM; k++){
    float av = a[k];
    acc0 += av*W1[k*FFD + t];
    acc1 += av*W1[k*FFD + t + 256];
  }
  hid[row*FFD + t]       = fmaxf(acc0, 0.f);
  hid[row*FFD + t + 256] = fmaxf(acc1, 0.f);
}

// ---------------- K9: FFN layer 2 + residual + LN3 -> fp32 out ----------------
__global__ void ffn2_ln_kernel(const float* __restrict__ hid, const float* __restrict__ W2,
                               const float* __restrict__ b2, const float* __restrict__ out4,
                               const float* __restrict__ g3, const float* __restrict__ b3,
                               float* __restrict__ out){
  int row = blockIdx.x, t = threadIdx.x;
  __shared__ float a[FFD]; __shared__ float tmp[256];
  a[t]       = hid[row*FFD + t];
  a[t + 256] = hid[row*FFD + t + 256];
  __syncthreads();
  float acc = b2[t] + out4[row*DM + t];
  #pragma unroll 8
  for (int k = 0; k < FFD; k++) acc += a[k]*W2[k*DM + t];
  float mean = blk_sum256(acc, tmp)*(1.f/DM);
  float c = acc - mean;
  float var = blk_sum256(c*c, tmp)*(1.f/DM);
  float o = c*rsqrtf(var + 1e-5f)*g3[t] + b3[t];
  out[row*DM + t] = o;
}

extern "C" void kernel_launch(void* const* d_in, const int* in_sizes, int n_in,
                              void* d_out, int out_size, void* d_ws, size_t ws_size,
                              hipStream_t stream) {
  const float* queries = (const float*)d_in[0];
  const float* bev     = (const float*)d_in[1];
  const float* ref     = (const float*)d_in[2];
  const float* og      = (const float*)d_in[3];
  const float* mask    = (const float*)d_in[4];
  const float* Wq = (const float*)d_in[5];  const float* bq = (const float*)d_in[6];
  const float* Wk = (const float*)d_in[7];  const float* bk = (const float*)d_in[8];
  const float* Wv = (const float*)d_in[9];  const float* bv = (const float*)d_in[10];
  const float* Wo = (const float*)d_in[11]; const float* bo = (const float*)d_in[12];
  const float* ln1g = (const float*)d_in[13]; const float* ln1b = (const float*)d_in[14];
  const float* Wval = (const float*)d_in[15]; const float* bval = (const float*)d_in[16];
  const float* Woff = (const float*)d_in[17]; const float* boff = (const float*)d_in[18];
  const float* Wattn = (const float*)d_in[19]; const float* battn = (const float*)d_in[20];
  const float* Wdo = (const float*)d_in[21]; const float* bdo = (const float*)d_in[22];
  const float* ln2g = (const float*)d_in[23]; const float* ln2b = (const float*)d_in[24];
  const float* W1 = (const float*)d_in[25]; const float* b1 = (const float*)d_in[26];
  const float* W2 = (const float*)d_in[27]; const float* b2 = (const float*)d_in[28];
  const float* ln3g = (const float*)d_in[29]; const float* ln3b = (const float*)d_in[30];

  const int M = NB*QN;            // 3600
  float* ws = (float*)d_ws;
  float* qh       = ws;                   // 921600
  float* kT       = qh + (size_t)M*DM;    // 921600  [n][h][d][k]
  float* vh       = kT + (size_t)M*DM;
  float* attn_out = vh + (size_t)M*DM;
  float* out2     = attn_out + (size_t)M*DM;
  float* aug      = out2 + (size_t)M*DM;
  float* out4     = aug + (size_t)M*DM;
  float* sampled  = out4 + (size_t)M*DM;
  float* hid      = sampled + (size_t)M*DM;       // 3600*512
  float* locb     = hid + (size_t)M*FFD;          // 3600*64
  float* awb      = locb + (size_t)M*64;          // 3600*32
  bf16*  value    = (bf16*)(awb + (size_t)M*32);  // 160000*256 bf16

  proj3_kernel<<<dim3(M/8, 3), 256, 0, stream>>>(queries, og, Wq, bq, Wk, bk, Wv, bv, qh, kT, vh);
  mha_kernel<<<dim3(QN/QT, HH, NB), 256, 0, stream>>>(qh, kT, vh, mask, attn_out);
  wo_ln_kernel<<<M, 256, 0, stream>>>(attn_out, Wo, bo, queries, og, ln1g, ln1b, out2, aug);
  value_gemm_mfma<<<dim3((NB*NV)/64, 4), 256, 0, stream>>>(bev, Wval, bval, value);
  off_attn_kernel<<<M, 128, 0, stream>>>(aug, ref, Woff, boff, Wattn, battn, locb, awb);
  deform_kernel<<<M, 256, 0, stream>>>(value, locb, awb, sampled);
  wdo_ln_kernel<<<M, 256, 0, stream>>>(sampled, Wdo, bdo, mask, out2, ln2g, ln2b, out4);
  ffn1_kernel<<<M, 256, 0, stream>>>(out4, W1, b1, hid);
  ffn2_ln_kernel<<<M, 256, 0, stream>>>(hid, W2, b2, out4, ln3g, ln3b, (float*)d_out);
}

// Round 5
// 668.223 us; speedup vs baseline: 2.2808x; 1.2921x over previous
//
#include <hip/hip_runtime.h>
#include <hip/hip_bf16.h>
#include <cstddef>

#define NB  4
#define QN  900
#define DM  256
#define HH  8
#define HD  32
#define PP  4
#define HBg 200
#define WBg 200
#define FFD 512
#define NV  (HBg*WBg)   // 40000 bev cells

typedef __hip_bfloat16 bf16;
typedef __attribute__((ext_vector_type(8))) short short8;
typedef __attribute__((ext_vector_type(4))) float floatx4;

__device__ __forceinline__ float bf2f(bf16 x){ return __bfloat162float(x); }
__device__ __forceinline__ unsigned short f2bu(float f){
  bf16 h = __float2bfloat16(f);
  return *(unsigned short*)&h;
}

__device__ __forceinline__ float blk_sum256(float v, float* tmp){
  int t = threadIdx.x;
  tmp[t] = v; __syncthreads();
  for (int s = 128; s > 0; s >>= 1){ if (t < s) tmp[t] += tmp[t+s]; __syncthreads(); }
  float r = tmp[0]; __syncthreads();
  return r;
}

// ---------------- K0: convert all weights to bf16 (one-shot) ----------------
__global__ void cvtW_kernel(const float* __restrict__ Wq, const float* __restrict__ Wk,
                            const float* __restrict__ Wv, const float* __restrict__ Wo,
                            const float* __restrict__ Wval, const float* __restrict__ Woff,
                            const float* __restrict__ Wattn, const float* __restrict__ Wdo,
                            const float* __restrict__ W1, const float* __restrict__ W2,
                            bf16* __restrict__ dst){
  int i = blockIdx.x*256 + threadIdx.x;
  if (i >= 679936) return;
  const float* s; int o;
  if      (i <  65536){ s=Wq;    o=0; }
  else if (i < 131072){ s=Wk;    o=65536; }
  else if (i < 196608){ s=Wv;    o=131072; }
  else if (i < 262144){ s=Wo;    o=196608; }
  else if (i < 327680){ s=Wval;  o=262144; }
  else if (i < 344064){ s=Woff;  o=327680; }
  else if (i < 352256){ s=Wattn; o=344064; }
  else if (i < 417792){ s=Wdo;   o=352256; }
  else if (i < 548864){ s=W1;    o=417792; }
  else                { s=W2;    o=548864; }
  dst[i] = __float2bfloat16(s[i-o]);
}

// ---------------- K1: q/k/v projections, 8 rows per block, bf16 out ----------------
// which==0 -> qh_b natural [row][256]; which==1 -> kh_b natural; which==2 -> vt[n][h][d][960]
__global__ void proj3_kernel(const float* __restrict__ queries, const float* __restrict__ og,
                             const bf16* __restrict__ Wq, const float* __restrict__ bq,
                             const bf16* __restrict__ Wk, const float* __restrict__ bk,
                             const bf16* __restrict__ Wv, const float* __restrict__ bv,
                             bf16* __restrict__ qh_b, bf16* __restrict__ kh_b, bf16* __restrict__ vt){
  int which = blockIdx.y, t = threadIdx.x;
  int row0 = blockIdx.x*8;
  __shared__ float aS[DM][9];
  for (int idx = t; idx < 8*DM; idx += 256){
    int r = idx >> 8, k = idx & 255;
    float v = queries[(size_t)(row0 + r)*DM + k];
    if (which != 2) v += og[(size_t)(row0 + r)*DM + k];
    aS[k][r] = v;
  }
  __syncthreads();
  const bf16* W; const float* b;
  if (which == 0){ W = Wq; b = bq; }
  else if (which == 1){ W = Wk; b = bk; }
  else { W = Wv; b = bv; }
  float bias = b[t];
  float acc[8];
  #pragma unroll
  for (int r = 0; r < 8; r++) acc[r] = bias;
  #pragma unroll 4
  for (int k = 0; k < DM; k++){
    float w = bf2f(W[k*DM + t]);
    floatx4 a0 = *(floatx4*)&aS[k][0];
    floatx4 a1 = *(floatx4*)&aS[k][4];
    acc[0] += a0.x*w; acc[1] += a0.y*w; acc[2] += a0.z*w; acc[3] += a0.w*w;
    acc[4] += a1.x*w; acc[5] += a1.y*w; acc[6] += a1.z*w; acc[7] += a1.w*w;
  }
  if (which == 2){
    int h = t >> 5, d = t & 31;
    #pragma unroll
    for (int r = 0; r < 8; r++){
      int row = row0 + r, n = row / QN, q = row - n*QN;
      vt[((size_t)((n*HH + h)*HD) + d)*960 + q] = __float2bfloat16(acc[r]);
    }
  } else {
    bf16* out = (which == 0) ? qh_b : kh_b;
    #pragma unroll
    for (int r = 0; r < 8; r++) out[(size_t)(row0 + r)*DM + t] = __float2bfloat16(acc[r]);
  }
}

// ---------------- K2: flash MHA, bf16 MFMA; block = 32 q-rows (2 waves x 16) ----------------
__global__ void __launch_bounds__(128) mha_flash(const bf16* __restrict__ qh_b,
                                                 const bf16* __restrict__ kh_b,
                                                 const bf16* __restrict__ vt,
                                                 const float* __restrict__ mask,
                                                 bf16* __restrict__ attn_b){
  int qt = blockIdx.x, h = blockIdx.y, n = blockIdx.z;
  int t = threadIdx.x, l = t & 63, w = t >> 6;
  int q0 = qt*32;
  __shared__ short Qs[32*40];
  __shared__ short Ks[64*40];
  __shared__ short Vts[32*72];
  __shared__ short Ps[2][16*72];
  // stage Q tile (32 rows x 32 d)
  {
    int r = t >> 2, q = t & 3;
    int qr = q0 + r; if (qr > QN-1) qr = QN-1;
    *(short8*)&Qs[r*40 + q*8] = *(const short8*)(const void*)(qh_b + (size_t)(n*QN + qr)*DM + h*32 + q*8);
  }
  floatx4 O[2]; O[0] = (floatx4){0,0,0,0}; O[1] = (floatx4){0,0,0,0};
  float mo[4] = {-1e30f,-1e30f,-1e30f,-1e30f};
  float li[4] = {0.f,0.f,0.f,0.f};
  int lm = l & 15, lq = l >> 4;
  const float scale = 0.17677669529663687f;
  for (int kt = 0; kt < 15; kt++){
    int kk0 = kt*64;
    __syncthreads();
    #pragma unroll
    for (int i = 0; i < 2; i++){
      int idx = t + i*128;
      int r = idx >> 2, q = idx & 3;
      int kr = kk0 + r; if (kr > QN-1) kr = QN-1;
      *(short8*)&Ks[r*40 + q*8] = *(const short8*)(const void*)(kh_b + (size_t)(n*QN + kr)*DM + h*32 + q*8);
    }
    #pragma unroll
    for (int i = 0; i < 2; i++){
      int idx = t + i*128;
      int d = idx >> 3, q = idx & 7;
      *(short8*)&Vts[d*72 + q*8] = *(const short8*)(const void*)(vt + ((size_t)((n*HH + h)*HD) + d)*960 + kk0 + q*8);
    }
    __syncthreads();
    // S = Q K^T : 16 rows x 64 keys per wave
    short8 af = *(short8*)&Qs[(w*16 + lm)*40 + lq*8];
    floatx4 S[4];
    #pragma unroll
    for (int tn = 0; tn < 4; tn++){
      short8 bfr = *(short8*)&Ks[(tn*16 + lm)*40 + lq*8];
      S[tn] = __builtin_amdgcn_mfma_f32_16x16x32_bf16(af, bfr, (floatx4){0,0,0,0}, 0, 0, 0);
    }
    // mask + scale
    #pragma unroll
    for (int tn = 0; tn < 4; tn++){
      int kk = kk0 + tn*16 + lm;
      int kc = kk > QN-1 ? QN-1 : kk;
      bool keep = (kk < QN) && (mask[(size_t)n*QN + kc] > 0.f);
      #pragma unroll
      for (int r = 0; r < 4; r++)
        S[tn][r] = keep ? S[tn][r]*scale : -1e9f;
    }
    // online softmax (per row = reg r, shared by 16-lane groups)
    float mnew[4], alpha[4];
    #pragma unroll
    for (int r = 0; r < 4; r++){
      float m = fmaxf(fmaxf(S[0][r], S[1][r]), fmaxf(S[2][r], S[3][r]));
      #pragma unroll
      for (int off = 1; off < 16; off <<= 1) m = fmaxf(m, __shfl_xor(m, off));
      mnew[r] = fmaxf(mo[r], m);
      alpha[r] = __expf(mo[r] - mnew[r]);
      mo[r] = mnew[r];
    }
    #pragma unroll
    for (int tn = 0; tn < 4; tn++)
      #pragma unroll
      for (int r = 0; r < 4; r++)
        S[tn][r] = __expf(S[tn][r] - mnew[r]);
    #pragma unroll
    for (int r = 0; r < 4; r++){
      float s = S[0][r] + S[1][r] + S[2][r] + S[3][r];
      #pragma unroll
      for (int off = 1; off < 16; off <<= 1) s += __shfl_xor(s, off);
      li[r] = li[r]*alpha[r] + s;
      O[0][r] *= alpha[r];
      O[1][r] *= alpha[r];
    }
    // P (C-layout) -> LDS in A-layout source form [row][key]
    #pragma unroll
    for (int tn = 0; tn < 4; tn++)
      #pragma unroll
      for (int r = 0; r < 4; r++)
        Ps[w][(lq*4 + r)*72 + tn*16 + lm] = (short)f2bu(S[tn][r]);
    __syncthreads();
    // O += P V  (k = 64 keys via 2 chained K=32 MFMAs)
    #pragma unroll
    for (int s = 0; s < 2; s++){
      short8 pf = *(short8*)&Ps[w][lm*72 + s*32 + lq*8];
      #pragma unroll
      for (int tn2 = 0; tn2 < 2; tn2++){
        short8 vf = *(short8*)&Vts[(tn2*16 + lm)*72 + s*32 + lq*8];
        O[tn2] = __builtin_amdgcn_mfma_f32_16x16x32_bf16(pf, vf, O[tn2], 0, 0, 0);
      }
    }
  }
  #pragma unroll
  for (int r = 0; r < 4; r++){
    int row = q0 + w*16 + lq*4 + r;
    if (row < QN){
      float inv = 1.f/li[r];
      attn_b[(size_t)(n*QN + row)*DM + h*32 + lm]      = __float2bfloat16(O[0][r]*inv);
      attn_b[(size_t)(n*QN + row)*DM + h*32 + 16 + lm] = __float2bfloat16(O[1][r]*inv);
    }
  }
}

// ---------------- K3: Wo GEMM + residual + LN1, write out2 and aug ----------------
__global__ void wo_ln_kernel(const bf16* __restrict__ attn_b,
                             const bf16* __restrict__ Wo, const float* __restrict__ bo,
                             const float* __restrict__ queries, const float* __restrict__ og,
                             const float* __restrict__ g1, const float* __restrict__ b1,
                             float* __restrict__ out2, float* __restrict__ aug){
  int row = blockIdx.x, t = threadIdx.x;
  __shared__ float a[DM]; __shared__ float tmp[256];
  a[t] = bf2f(attn_b[(size_t)row*DM + t]); __syncthreads();
  float acc = bo[t] + queries[(size_t)row*DM + t];
  #pragma unroll 8
  for (int k = 0; k < DM; k++) acc += a[k]*bf2f(Wo[k*DM + t]);
  float mean = blk_sum256(acc, tmp)*(1.f/DM);
  float c = acc - mean;
  float var = blk_sum256(c*c, tmp)*(1.f/DM);
  float o = c*rsqrtf(var + 1e-5f)*g1[t] + b1[t];
  out2[(size_t)row*DM + t] = o;
  aug[(size_t)row*DM + t]  = o + og[(size_t)row*DM + t];
}

// ---------------- K4: value = bev @ Wval + bval, bf16 MFMA 64x64 tile ----------------
__global__ void value_gemm_mfma(const float* __restrict__ bev, const bf16* __restrict__ Wval,
                                const float* __restrict__ bval, bf16* __restrict__ value){
  int t = threadIdx.x;
  int l = t & 63, w = t >> 6;
  int wm = w >> 1, wn = w & 1;
  long row0 = (long)blockIdx.x*64;
  int n0 = blockIdx.y*64;
  __shared__ __align__(16) short As[64*40];
  __shared__ __align__(16) short Bs[64*40];

  floatx4 acc[2][2];
  #pragma unroll
  for (int tm = 0; tm < 2; tm++)
    #pragma unroll
    for (int tn = 0; tn < 2; tn++){
      float b = bval[n0 + wn*32 + tn*16 + (l & 15)];
      acc[tm][tn] = (floatx4){b, b, b, b};
    }

  for (int kt = 0; kt < 8; kt++){
    int k0 = kt*32;
    #pragma unroll
    for (int i = 0; i < 4; i++){
      int p = t + i*256;
      int r = p >> 4, c2 = p & 15;
      const float2* ap = (const float2*)(bev + (size_t)(row0 + r)*DM + k0);
      float2 v = ap[c2];
      unsigned int pk = (unsigned int)f2bu(v.x) | ((unsigned int)f2bu(v.y) << 16);
      *(unsigned int*)&As[r*40 + c2*2] = pk;
    }
    #pragma unroll
    for (int i = 0; i < 4; i++){
      int p = t + i*256;
      int k = p >> 5, n2 = p & 31;
      unsigned int v = *(const unsigned int*)(const void*)(Wval + (size_t)(k0 + k)*DM + n0 + n2*2);
      Bs[(n2*2)*40 + k]     = (short)(v & 0xffff);
      Bs[(n2*2 + 1)*40 + k] = (short)(v >> 16);
    }
    __syncthreads();
    short8 af[2], bfr[2];
    #pragma unroll
    for (int tm = 0; tm < 2; tm++)
      af[tm] = *(short8*)&As[(wm*32 + tm*16 + (l & 15))*40 + (l >> 4)*8];
    #pragma unroll
    for (int tn = 0; tn < 2; tn++)
      bfr[tn] = *(short8*)&Bs[(wn*32 + tn*16 + (l & 15))*40 + (l >> 4)*8];
    #pragma unroll
    for (int tm = 0; tm < 2; tm++)
      #pragma unroll
      for (int tn = 0; tn < 2; tn++)
        acc[tm][tn] = __builtin_amdgcn_mfma_f32_16x16x32_bf16(af[tm], bfr[tn], acc[tm][tn], 0, 0, 0);
    __syncthreads();
  }
  #pragma unroll
  for (int tm = 0; tm < 2; tm++)
    #pragma unroll
    for (int tn = 0; tn < 2; tn++){
      long grow = row0 + wm*32 + tm*16 + (l >> 4)*4;
      int gcol = n0 + wn*32 + tn*16 + (l & 15);
      #pragma unroll
      for (int r = 0; r < 4; r++)
        value[(grow + r)*DM + gcol] = __float2bfloat16(acc[tm][tn][r]);
    }
}

// ---------------- K5: offsets + attention-weight softmax + sample coords ----------------
__global__ void off_attn_kernel(const float* __restrict__ aug, const float* __restrict__ ref,
                                const bf16* __restrict__ Woff, const float* __restrict__ boff,
                                const bf16* __restrict__ Wattn, const float* __restrict__ battn,
                                float* __restrict__ locb, float* __restrict__ awb){
  int row = blockIdx.x, t = threadIdx.x; // 128 threads
  __shared__ float a[DM]; __shared__ float offL[64]; __shared__ float awL[32];
  a[t]       = aug[(size_t)row*DM + t];
  a[t + 128] = aug[(size_t)row*DM + t + 128];
  __syncthreads();
  if (t < 64){
    float acc = boff[t];
    for (int k = 0; k < DM; k++) acc += a[k]*bf2f(Woff[k*64 + t]);
    offL[t] = acc;
  } else if (t < 96){
    int j = t - 64;
    float acc = battn[j];
    for (int k = 0; k < DM; k++) acc += a[k]*bf2f(Wattn[k*32 + j]);
    awL[j] = acc;
  }
  __syncthreads();
  if (t < 64){
    int c = t & 1;
    float refv = ref[row*2 + c];
    locb[row*64 + t] = refv*200.0f + offL[t] - 0.5f;
  }
  if (t < 8){
    float m = -1e30f;
    #pragma unroll
    for (int p = 0; p < 4; p++) m = fmaxf(m, awL[t*4 + p]);
    float e[4]; float sm = 0.f;
    #pragma unroll
    for (int p = 0; p < 4; p++){ e[p] = __expf(awL[t*4 + p] - m); sm += e[p]; }
    #pragma unroll
    for (int p = 0; p < 4; p++) awb[row*32 + t*4 + p] = e[p]/sm;
  }
}

// ---------------- K6: bilinear deformable sampling + weight over P ----------------
__global__ void deform_kernel(const bf16* __restrict__ value, const float* __restrict__ locb,
                              const float* __restrict__ awb, float* __restrict__ sampled){
  int row = blockIdx.x, t = threadIdx.x;
  int n = row / QN;
  __shared__ float locS[64]; __shared__ float awS[32];
  if (t < 64) locS[t] = locb[row*64 + t];
  else if (t < 96) awS[t - 64] = awb[row*32 + (t - 64)];
  __syncthreads();
  int h = t >> 5, d = t & 31;
  const bf16* vbase = value + (long)n*NV*DM + h*HD + d;
  float acc = 0.f;
  #pragma unroll
  for (int p = 0; p < PP; p++){
    float x = locS[h*8 + p*2], y = locS[h*8 + p*2 + 1];
    float w = awS[h*4 + p];
    float x0 = floorf(x), y0 = floorf(y);
    float fx = x - x0, fy = y - y0;
    int xi = (int)x0, yi = (int)y0;
    #pragma unroll
    for (int dy = 0; dy < 2; dy++){
      #pragma unroll
      for (int dx = 0; dx < 2; dx++){
        int xc = xi + dx, yc = yi + dy;
        float wg = (dx ? fx : 1.f - fx)*(dy ? fy : 1.f - fy);
        if (xc >= 0 && xc < WBg && yc >= 0 && yc < HBg){
          acc += w*wg*bf2f(vbase[(long)(yc*WBg + xc)*DM]);
        }
      }
    }
  }
  sampled[(size_t)row*DM + t] = acc;
}

// ---------------- K7: Wdo GEMM + mask + residual + LN2 -> out4 bf16 ----------------
__global__ void wdo_ln_kernel(const float* __restrict__ sampled,
                              const bf16* __restrict__ Wdo, const float* __restrict__ bdo,
                              const float* __restrict__ mask, const float* __restrict__ out2,
                              const float* __restrict__ g2, const float* __restrict__ b2,
                              bf16* __restrict__ out4_b){
  int row = blockIdx.x, t = threadIdx.x;
  __shared__ float a[DM]; __shared__ float tmp[256];
  a[t] = sampled[(size_t)row*DM + t]; __syncthreads();
  float acc = bdo[t];
  #pragma unroll 8
  for (int k = 0; k < DM; k++) acc += a[k]*bf2f(Wdo[k*DM + t]);
  acc = acc*mask[row] + out2[(size_t)row*DM + t];
  float mean = blk_sum256(acc, tmp)*(1.f/DM);
  float c = acc - mean;
  float var = blk_sum256(c*c, tmp)*(1.f/DM);
  float o = c*rsqrtf(var + 1e-5f)*g2[t] + b2[t];
  out4_b[(size_t)row*DM + t] = __float2bfloat16(o);
}

// ---------------- K8: FFN layer 1 (relu) ----------------
__global__ void ffn1_kernel(const bf16* __restrict__ out4_b, const bf16* __restrict__ W1,
                            const float* __restrict__ b1, float* __restrict__ hid){
  int row = blockIdx.x, t = threadIdx.x;
  __shared__ float a[DM];
  a[t] = bf2f(out4_b[(size_t)row*DM + t]); __syncthreads();
  float acc0 = b1[t], acc1 = b1[t + 256];
  #pragma unroll 8
  for (int k = 0; k < DM; k++){
    float av = a[k];
    acc0 += av*bf2f(W1[k*FFD + t]);
    acc1 += av*bf2f(W1[k*FFD + t + 256]);
  }
  hid[(size_t)row*FFD + t]       = fmaxf(acc0, 0.f);
  hid[(size_t)row*FFD + t + 256] = fmaxf(acc1, 0.f);
}

// ---------------- K9: FFN layer 2 + residual + LN3 -> fp32 out ----------------
__global__ void ffn2_ln_kernel(const float* __restrict__ hid, const bf16* __restrict__ W2,
                               const float* __restrict__ b2, const bf16* __restrict__ out4_b,
                               const float* __restrict__ g3, const float* __restrict__ b3,
                               float* __restrict__ out){
  int row = blockIdx.x, t = threadIdx.x;
  __shared__ float a[FFD]; __shared__ float tmp[256];
  a[t]       = hid[(size_t)row*FFD + t];
  a[t + 256] = hid[(size_t)row*FFD + t + 256];
  __syncthreads();
  float acc = b2[t] + bf2f(out4_b[(size_t)row*DM + t]);
  #pragma unroll 8
  for (int k = 0; k < FFD; k++) acc += a[k]*bf2f(W2[k*DM + t]);
  float mean = blk_sum256(acc, tmp)*(1.f/DM);
  float c = acc - mean;
  float var = blk_sum256(c*c, tmp)*(1.f/DM);
  float o = c*rsqrtf(var + 1e-5f)*g3[t] + b3[t];
  out[(size_t)row*DM + t] = o;
}

extern "C" void kernel_launch(void* const* d_in, const int* in_sizes, int n_in,
                              void* d_out, int out_size, void* d_ws, size_t ws_size,
                              hipStream_t stream) {
  const float* queries = (const float*)d_in[0];
  const float* bev     = (const float*)d_in[1];
  const float* ref     = (const float*)d_in[2];
  const float* og      = (const float*)d_in[3];
  const float* mask    = (const float*)d_in[4];
  const float* Wq = (const float*)d_in[5];  const float* bq = (const float*)d_in[6];
  const float* Wk = (const float*)d_in[7];  const float* bk = (const float*)d_in[8];
  const float* Wv = (const float*)d_in[9];  const float* bv = (const float*)d_in[10];
  const float* Wo = (const float*)d_in[11]; const float* bo = (const float*)d_in[12];
  const float* ln1g = (const float*)d_in[13]; const float* ln1b = (const float*)d_in[14];
  const float* Wval = (const float*)d_in[15]; const float* bval = (const float*)d_in[16];
  const float* Woff = (const float*)d_in[17]; const float* boff = (const float*)d_in[18];
  const float* Wattn = (const float*)d_in[19]; const float* battn = (const float*)d_in[20];
  const float* Wdo = (const float*)d_in[21]; const float* bdo = (const float*)d_in[22];
  const float* ln2g = (const float*)d_in[23]; const float* ln2b = (const float*)d_in[24];
  const float* W1 = (const float*)d_in[25]; const float* b1 = (const float*)d_in[26];
  const float* W2 = (const float*)d_in[27]; const float* b2 = (const float*)d_in[28];
  const float* ln3g = (const float*)d_in[29]; const float* ln3b = (const float*)d_in[30];

  const int M = NB*QN;            // 3600
  char* base = (char*)d_ws;
  bf16*  Wb      = (bf16*)base;                      base += 1359872;   // 679936 bf16
  bf16*  qh_b    = (bf16*)base;                      base += 1843200;
  bf16*  kh_b    = (bf16*)base;                      base += 1843200;
  bf16*  vt      = (bf16*)base;                      base += 1966080;   // [1024][960]
  bf16*  attn_b  = (bf16*)base;                      base += 1843200;
  float* out2    = (float*)base;                     base += 3686400;
  float* aug     = (float*)base;                     base += 3686400;
  float* sampled = (float*)base;                     base += 3686400;
  bf16*  out4_b  = (bf16*)base;                      base += 1843200;
  float* hid     = (float*)base;                     base += 7372800;
  float* locb    = (float*)base;                     base += 921600;
  float* awb     = (float*)base;                     base += 460800;
  bf16*  value   = (bf16*)base;                      // 81,920,000 bytes

  bf16* Wqb    = Wb;
  bf16* Wkb    = Wb + 65536;
  bf16* Wvb    = Wb + 131072;
  bf16* Wob    = Wb + 196608;
  bf16* Wvalb  = Wb + 262144;
  bf16* Woffb  = Wb + 327680;
  bf16* Wattnb = Wb + 344064;
  bf16* Wdob   = Wb + 352256;
  bf16* W1b    = Wb + 417792;
  bf16* W2b    = Wb + 548864;

  cvtW_kernel<<<2656, 256, 0, stream>>>(Wq, Wk, Wv, Wo, Wval, Woff, Wattn, Wdo, W1, W2, Wb);
  proj3_kernel<<<dim3(M/8, 3), 256, 0, stream>>>(queries, og, Wqb, bq, Wkb, bk, Wvb, bv, qh_b, kh_b, vt);
  mha_flash<<<dim3(29, HH, NB), 128, 0, stream>>>(qh_b, kh_b, vt, mask, attn_b);
  wo_ln_kernel<<<M, 256, 0, stream>>>(attn_b, Wob, bo, queries, og, ln1g, ln1b, out2, aug);
  value_gemm_mfma<<<dim3((NB*NV)/64, 4), 256, 0, stream>>>(bev, Wvalb, bval, value);
  off_attn_kernel<<<M, 128, 0, stream>>>(aug, ref, Woffb, boff, Wattnb, battn, locb, awb);
  deform_kernel<<<M, 256, 0, stream>>>(value, locb, awb, sampled);
  wdo_ln_kernel<<<M, 256, 0, stream>>>(sampled, Wdob, bdo, mask, out2, ln2g, ln2b, out4_b);
  ffn1_kernel<<<M, 256, 0, stream>>>(out4_b, W1b, b1, hid);
  ffn2_ln_kernel<<<M, 256, 0, stream>>>(hid, W2b, b2, out4_b, ln3g, ln3b, (float*)d_out);
}

// Round 6
// 661.813 us; speedup vs baseline: 2.3029x; 1.0097x over previous
//
#include <hip/hip_runtime.h>
#include <hip/hip_bf16.h>
#include <cstddef>

#define NB  4
#define QN  900
#define DM  256
#define HH  8
#define HD  32
#define PP  4
#define HBg 200
#define WBg 200
#define FFD 512
#define NV  (HBg*WBg)   // 40000 bev cells

typedef __hip_bfloat16 bf16;
typedef __attribute__((ext_vector_type(8))) short short8;
typedef __attribute__((ext_vector_type(4))) float floatx4;

__device__ __forceinline__ float bf2f(bf16 x){ return __bfloat162float(x); }
__device__ __forceinline__ unsigned short f2bu(float f){
  bf16 h = __float2bfloat16(f);
  return *(unsigned short*)&h;
}

__device__ __forceinline__ float blk_sum256(float v, float* tmp){
  int t = threadIdx.x;
  tmp[t] = v; __syncthreads();
  for (int s = 128; s > 0; s >>= 1){ if (t < s) tmp[t] += tmp[t+s]; __syncthreads(); }
  float r = tmp[0]; __syncthreads();
  return r;
}

// ---------------- K0: convert all weights to bf16 (one-shot) ----------------
__global__ void cvtW_kernel(const float* __restrict__ Wq, const float* __restrict__ Wk,
                            const float* __restrict__ Wv, const float* __restrict__ Wo,
                            const float* __restrict__ Wval, const float* __restrict__ Woff,
                            const float* __restrict__ Wattn, const float* __restrict__ Wdo,
                            const float* __restrict__ W1, const float* __restrict__ W2,
                            bf16* __restrict__ dst){
  int i = blockIdx.x*256 + threadIdx.x;
  if (i >= 679936) return;
  const float* s; int o;
  if      (i <  65536){ s=Wq;    o=0; }
  else if (i < 131072){ s=Wk;    o=65536; }
  else if (i < 196608){ s=Wv;    o=131072; }
  else if (i < 262144){ s=Wo;    o=196608; }
  else if (i < 327680){ s=Wval;  o=262144; }
  else if (i < 344064){ s=Woff;  o=327680; }
  else if (i < 352256){ s=Wattn; o=344064; }
  else if (i < 417792){ s=Wdo;   o=352256; }
  else if (i < 548864){ s=W1;    o=417792; }
  else                { s=W2;    o=548864; }
  dst[i] = __float2bfloat16(s[i-o]);
}

// ---------------- K0b: Wval transposed bf16 [n][k] ----------------
__global__ void cvtWvalT_kernel(const float* __restrict__ Wval, bf16* __restrict__ WvalT){
  int k = blockIdx.x, n = threadIdx.x;
  WvalT[(size_t)n*DM + k] = __float2bfloat16(Wval[(size_t)k*DM + n]);
}

// ---------------- K1: q/k/v projections, 8 rows per block, bf16 out ----------------
__global__ void proj3_kernel(const float* __restrict__ queries, const float* __restrict__ og,
                             const bf16* __restrict__ Wq, const float* __restrict__ bq,
                             const bf16* __restrict__ Wk, const float* __restrict__ bk,
                             const bf16* __restrict__ Wv, const float* __restrict__ bv,
                             bf16* __restrict__ qh_b, bf16* __restrict__ kh_b, bf16* __restrict__ vt){
  int which = blockIdx.y, t = threadIdx.x;
  int row0 = blockIdx.x*8;
  __shared__ float aS[DM][9];
  for (int idx = t; idx < 8*DM; idx += 256){
    int r = idx >> 8, k = idx & 255;
    float v = queries[(size_t)(row0 + r)*DM + k];
    if (which != 2) v += og[(size_t)(row0 + r)*DM + k];
    aS[k][r] = v;
  }
  __syncthreads();
  const bf16* W; const float* b;
  if (which == 0){ W = Wq; b = bq; }
  else if (which == 1){ W = Wk; b = bk; }
  else { W = Wv; b = bv; }
  float bias = b[t];
  float acc[8];
  #pragma unroll
  for (int r = 0; r < 8; r++) acc[r] = bias;
  #pragma unroll 4
  for (int k = 0; k < DM; k++){
    float w = bf2f(W[k*DM + t]);
    floatx4 a0 = *(floatx4*)&aS[k][0];
    floatx4 a1 = *(floatx4*)&aS[k][4];
    acc[0] += a0.x*w; acc[1] += a0.y*w; acc[2] += a0.z*w; acc[3] += a0.w*w;
    acc[4] += a1.x*w; acc[5] += a1.y*w; acc[6] += a1.z*w; acc[7] += a1.w*w;
  }
  if (which == 2){
    int h = t >> 5, d = t & 31;
    #pragma unroll
    for (int r = 0; r < 8; r++){
      int row = row0 + r, n = row / QN, q = row - n*QN;
      vt[((size_t)((n*HH + h)*HD) + d)*960 + q] = __float2bfloat16(acc[r]);
    }
  } else {
    bf16* out = (which == 0) ? qh_b : kh_b;
    #pragma unroll
    for (int r = 0; r < 8; r++) out[(size_t)(row0 + r)*DM + t] = __float2bfloat16(acc[r]);
  }
}

// ---------------- K2: flash MHA, bf16 MFMA; block = 32 q-rows (2 waves x 16) ----------------
__global__ void __launch_bounds__(128) mha_flash(const bf16* __restrict__ qh_b,
                                                 const bf16* __restrict__ kh_b,
                                                 const bf16* __restrict__ vt,
                                                 const float* __restrict__ mask,
                                                 bf16* __restrict__ attn_b){
  int qt = blockIdx.x, h = blockIdx.y, n = blockIdx.z;
  int t = threadIdx.x, l = t & 63, w = t >> 6;
  int q0 = qt*32;
  __shared__ short Qs[32*40];
  __shared__ short Ks[64*40];
  __shared__ short Vts[32*72];
  __shared__ short Ps[2][16*72];
  {
    int r = t >> 2, q = t & 3;
    int qr = q0 + r; if (qr > QN-1) qr = QN-1;
    *(short8*)&Qs[r*40 + q*8] = *(const short8*)(const void*)(qh_b + (size_t)(n*QN + qr)*DM + h*32 + q*8);
  }
  floatx4 O[2]; O[0] = (floatx4){0,0,0,0}; O[1] = (floatx4){0,0,0,0};
  float mo[4] = {-1e30f,-1e30f,-1e30f,-1e30f};
  float li[4] = {0.f,0.f,0.f,0.f};
  int lm = l & 15, lq = l >> 4;
  const float scale = 0.17677669529663687f;
  for (int kt = 0; kt < 15; kt++){
    int kk0 = kt*64;
    __syncthreads();
    #pragma unroll
    for (int i = 0; i < 2; i++){
      int idx = t + i*128;
      int r = idx >> 2, q = idx & 3;
      int kr = kk0 + r; if (kr > QN-1) kr = QN-1;
      *(short8*)&Ks[r*40 + q*8] = *(const short8*)(const void*)(kh_b + (size_t)(n*QN + kr)*DM + h*32 + q*8);
    }
    #pragma unroll
    for (int i = 0; i < 2; i++){
      int idx = t + i*128;
      int d = idx >> 3, q = idx & 7;
      *(short8*)&Vts[d*72 + q*8] = *(const short8*)(const void*)(vt + ((size_t)((n*HH + h)*HD) + d)*960 + kk0 + q*8);
    }
    __syncthreads();
    short8 af = *(short8*)&Qs[(w*16 + lm)*40 + lq*8];
    floatx4 S[4];
    #pragma unroll
    for (int tn = 0; tn < 4; tn++){
      short8 bfr = *(short8*)&Ks[(tn*16 + lm)*40 + lq*8];
      S[tn] = __builtin_amdgcn_mfma_f32_16x16x32_bf16(af, bfr, (floatx4){0,0,0,0}, 0, 0, 0);
    }
    #pragma unroll
    for (int tn = 0; tn < 4; tn++){
      int kk = kk0 + tn*16 + lm;
      int kc = kk > QN-1 ? QN-1 : kk;
      bool keep = (kk < QN) && (mask[(size_t)n*QN + kc] > 0.f);
      #pragma unroll
      for (int r = 0; r < 4; r++)
        S[tn][r] = keep ? S[tn][r]*scale : -1e9f;
    }
    float mnew[4], alpha[4];
    #pragma unroll
    for (int r = 0; r < 4; r++){
      float m = fmaxf(fmaxf(S[0][r], S[1][r]), fmaxf(S[2][r], S[3][r]));
      #pragma unroll
      for (int off = 1; off < 16; off <<= 1) m = fmaxf(m, __shfl_xor(m, off));
      mnew[r] = fmaxf(mo[r], m);
      alpha[r] = __expf(mo[r] - mnew[r]);
      mo[r] = mnew[r];
    }
    #pragma unroll
    for (int tn = 0; tn < 4; tn++)
      #pragma unroll
      for (int r = 0; r < 4; r++)
        S[tn][r] = __expf(S[tn][r] - mnew[r]);
    #pragma unroll
    for (int r = 0; r < 4; r++){
      float s = S[0][r] + S[1][r] + S[2][r] + S[3][r];
      #pragma unroll
      for (int off = 1; off < 16; off <<= 1) s += __shfl_xor(s, off);
      li[r] = li[r]*alpha[r] + s;
      O[0][r] *= alpha[r];
      O[1][r] *= alpha[r];
    }
    #pragma unroll
    for (int tn = 0; tn < 4; tn++)
      #pragma unroll
      for (int r = 0; r < 4; r++)
        Ps[w][(lq*4 + r)*72 + tn*16 + lm] = (short)f2bu(S[tn][r]);
    __syncthreads();
    #pragma unroll
    for (int s = 0; s < 2; s++){
      short8 pf = *(short8*)&Ps[w][lm*72 + s*32 + lq*8];
      #pragma unroll
      for (int tn2 = 0; tn2 < 2; tn2++){
        short8 vf = *(short8*)&Vts[(tn2*16 + lm)*72 + s*32 + lq*8];
        O[tn2] = __builtin_amdgcn_mfma_f32_16x16x32_bf16(pf, vf, O[tn2], 0, 0, 0);
      }
    }
  }
  #pragma unroll
  for (int r = 0; r < 4; r++){
    int row = q0 + w*16 + lq*4 + r;
    if (row < QN){
      float inv = 1.f/li[r];
      attn_b[(size_t)(n*QN + row)*DM + h*32 + lm]      = __float2bfloat16(O[0][r]*inv);
      attn_b[(size_t)(n*QN + row)*DM + h*32 + 16 + lm] = __float2bfloat16(O[1][r]*inv);
    }
  }
}

// ---------------- K3: Wo GEMM + residual + LN1, write out2 and aug ----------------
__global__ void wo_ln_kernel(const bf16* __restrict__ attn_b,
                             const bf16* __restrict__ Wo, const float* __restrict__ bo,
                             const float* __restrict__ queries, const float* __restrict__ og,
                             const float* __restrict__ g1, const float* __restrict__ b1,
                             float* __restrict__ out2, float* __restrict__ aug){
  int row = blockIdx.x, t = threadIdx.x;
  __shared__ float a[DM]; __shared__ float tmp[256];
  a[t] = bf2f(attn_b[(size_t)row*DM + t]); __syncthreads();
  float acc = bo[t] + queries[(size_t)row*DM + t];
  #pragma unroll 8
  for (int k = 0; k < DM; k++) acc += a[k]*bf2f(Wo[k*DM + t]);
  float mean = blk_sum256(acc, tmp)*(1.f/DM);
  float c = acc - mean;
  float var = blk_sum256(c*c, tmp)*(1.f/DM);
  float o = c*rsqrtf(var + 1e-5f)*g1[t] + b1[t];
  out2[(size_t)row*DM + t] = o;
  aug[(size_t)row*DM + t]  = o + og[(size_t)row*DM + t];
}

// ---------------- K4: value = bev @ Wval + bval; 64 rows x 256 cols per block ----------------
__global__ void __launch_bounds__(256) value_gemm_mfma(const float* __restrict__ bev,
                                const bf16* __restrict__ WvalT,   // [n][k]
                                const float* __restrict__ bval, bf16* __restrict__ value){
  int t = threadIdx.x;
  int l = t & 63, w = t >> 6;          // wave w -> cols w*64..w*64+63
  int lm = l & 15, lq = l >> 4;
  long row0 = (long)blockIdx.x*64;
  __shared__ __align__(16) short As[64*40];   // [r][k] bf16, stride 40 (2-way read alias = free)

  floatx4 acc[4][4];
  #pragma unroll
  for (int tn = 0; tn < 4; tn++){
    float b = bval[w*64 + tn*16 + lm];
    #pragma unroll
    for (int tm = 0; tm < 4; tm++) acc[tm][tn] = (floatx4){b, b, b, b};
  }

  for (int kt = 0; kt < 8; kt++){
    int k0 = kt*32;
    __syncthreads();
    // stage A: 64 rows x 32 k, fp32->bf16 packed, b64 writes
    #pragma unroll
    for (int i = 0; i < 2; i++){
      int idx = t + i*256;            // 0..511
      int r = idx >> 3, kq = idx & 7; // k = kq*4
      float4 v = *(const float4*)(bev + (size_t)(row0 + r)*DM + k0 + kq*4);
      unsigned int p0 = (unsigned int)f2bu(v.x) | ((unsigned int)f2bu(v.y) << 16);
      unsigned int p1 = (unsigned int)f2bu(v.z) | ((unsigned int)f2bu(v.w) << 16);
      uint2 pk; pk.x = p0; pk.y = p1;
      *(uint2*)&As[r*40 + kq*4] = pk;
    }
    __syncthreads();
    // B frags direct from global (L1/L2-resident 128KB)
    short8 bfr[4];
    #pragma unroll
    for (int tn = 0; tn < 4; tn++)
      bfr[tn] = *(const short8*)(const void*)(WvalT + (size_t)(w*64 + tn*16 + lm)*DM + k0 + lq*8);
    #pragma unroll
    for (int tm = 0; tm < 4; tm++){
      short8 af = *(short8*)&As[(tm*16 + lm)*40 + lq*8];
      #pragma unroll
      for (int tn = 0; tn < 4; tn++)
        acc[tm][tn] = __builtin_amdgcn_mfma_f32_16x16x32_bf16(af, bfr[tn], acc[tm][tn], 0, 0, 0);
    }
  }
  // C/D: col = lane&15, row = (lane>>4)*4 + reg
  #pragma unroll
  for (int tm = 0; tm < 4; tm++){
    long grow = row0 + tm*16 + lq*4;
    #pragma unroll
    for (int tn = 0; tn < 4; tn++){
      int gcol = w*64 + tn*16 + lm;
      #pragma unroll
      for (int r = 0; r < 4; r++)
        value[(grow + r)*DM + gcol] = __float2bfloat16(acc[tm][tn][r]);
    }
  }
}

// ---------------- K5: offsets + attention-weight softmax + sample coords ----------------
__global__ void off_attn_kernel(const float* __restrict__ aug, const float* __restrict__ ref,
                                const bf16* __restrict__ Woff, const float* __restrict__ boff,
                                const bf16* __restrict__ Wattn, const float* __restrict__ battn,
                                float* __restrict__ locb, float* __restrict__ awb){
  int row = blockIdx.x, t = threadIdx.x; // 128 threads
  __shared__ float a[DM]; __shared__ float offL[64]; __shared__ float awL[32];
  a[t]       = aug[(size_t)row*DM + t];
  a[t + 128] = aug[(size_t)row*DM + t + 128];
  __syncthreads();
  if (t < 64){
    float acc = boff[t];
    for (int k = 0; k < DM; k++) acc += a[k]*bf2f(Woff[k*64 + t]);
    offL[t] = acc;
  } else if (t < 96){
    int j = t - 64;
    float acc = battn[j];
    for (int k = 0; k < DM; k++) acc += a[k]*bf2f(Wattn[k*32 + j]);
    awL[j] = acc;
  }
  __syncthreads();
  if (t < 64){
    int c = t & 1;
    float refv = ref[row*2 + c];
    locb[row*64 + t] = refv*200.0f + offL[t] - 0.5f;
  }
  if (t < 8){
    float m = -1e30f;
    #pragma unroll
    for (int p = 0; p < 4; p++) m = fmaxf(m, awL[t*4 + p]);
    float e[4]; float sm = 0.f;
    #pragma unroll
    for (int p = 0; p < 4; p++){ e[p] = __expf(awL[t*4 + p] - m); sm += e[p]; }
    #pragma unroll
    for (int p = 0; p < 4; p++) awb[row*32 + t*4 + p] = e[p]/sm;
  }
}

// ---------------- K6: bilinear deformable sampling + weight over P ----------------
__global__ void deform_kernel(const bf16* __restrict__ value, const float* __restrict__ locb,
                              const float* __restrict__ awb, float* __restrict__ sampled){
  int row = blockIdx.x, t = threadIdx.x;
  int n = row / QN;
  __shared__ float locS[64]; __shared__ float awS[32];
  if (t < 64) locS[t] = locb[row*64 + t];
  else if (t < 96) awS[t - 64] = awb[row*32 + (t - 64)];
  __syncthreads();
  int h = t >> 5, d = t & 31;
  const bf16* vbase = value + (long)n*NV*DM + h*HD + d;
  float acc = 0.f;
  #pragma unroll
  for (int p = 0; p < PP; p++){
    float x = locS[h*8 + p*2], y = locS[h*8 + p*2 + 1];
    float w = awS[h*4 + p];
    float x0 = floorf(x), y0 = floorf(y);
    float fx = x - x0, fy = y - y0;
    int xi = (int)x0, yi = (int)y0;
    #pragma unroll
    for (int dy = 0; dy < 2; dy++){
      #pragma unroll
      for (int dx = 0; dx < 2; dx++){
        int xc = xi + dx, yc = yi + dy;
        float wg = (dx ? fx : 1.f - fx)*(dy ? fy : 1.f - fy);
        if (xc >= 0 && xc < WBg && yc >= 0 && yc < HBg){
          acc += w*wg*bf2f(vbase[(long)(yc*WBg + xc)*DM]);
        }
      }
    }
  }
  sampled[(size_t)row*DM + t] = acc;
}

// ---------------- K7: Wdo GEMM + mask + residual + LN2 -> out4 bf16 ----------------
__global__ void wdo_ln_kernel(const float* __restrict__ sampled,
                              const bf16* __restrict__ Wdo, const float* __restrict__ bdo,
                              const float* __restrict__ mask, const float* __restrict__ out2,
                              const float* __restrict__ g2, const float* __restrict__ b2,
                              bf16* __restrict__ out4_b){
  int row = blockIdx.x, t = threadIdx.x;
  __shared__ float a[DM]; __shared__ float tmp[256];
  a[t] = sampled[(size_t)row*DM + t]; __syncthreads();
  float acc = bdo[t];
  #pragma unroll 8
  for (int k = 0; k < DM; k++) acc += a[k]*bf2f(Wdo[k*DM + t]);
  acc = acc*mask[row] + out2[(size_t)row*DM + t];
  float mean = blk_sum256(acc, tmp)*(1.f/DM);
  float c = acc - mean;
  float var = blk_sum256(c*c, tmp)*(1.f/DM);
  float o = c*rsqrtf(var + 1e-5f)*g2[t] + b2[t];
  out4_b[(size_t)row*DM + t] = __float2bfloat16(o);
}

// ---------------- K8: FFN layer 1 (relu) ----------------
__global__ void ffn1_kernel(const bf16* __restrict__ out4_b, const bf16* __restrict__ W1,
                            const float* __restrict__ b1, float* __restrict__ hid){
  int row = blockIdx.x, t = threadIdx.x;
  __shared__ float a[DM];
  a[t] = bf2f(out4_b[(size_t)row*DM + t]); __syncthreads();
  float acc0 = b1[t], acc1 = b1[t + 256];
  #pragma unroll 8
  for (int k = 0; k < DM; k++){
    float av = a[k];
    acc0 += av*bf2f(W1[k*FFD + t]);
    acc1 += av*bf2f(W1[k*FFD + t + 256]);
  }
  hid[(size_t)row*FFD + t]       = fmaxf(acc0, 0.f);
  hid[(size_t)row*FFD + t + 256] = fmaxf(acc1, 0.f);
}

// ---------------- K9: FFN layer 2 + residual + LN3 -> fp32 out ----------------
__global__ void ffn2_ln_kernel(const float* __restrict__ hid, const bf16* __restrict__ W2,
                               const float* __restrict__ b2, const bf16* __restrict__ out4_b,
                               const float* __restrict__ g3, const float* __restrict__ b3,
                               float* __restrict__ out){
  int row = blockIdx.x, t = threadIdx.x;
  __shared__ float a[FFD]; __shared__ float tmp[256];
  a[t]       = hid[(size_t)row*FFD + t];
  a[t + 256] = hid[(size_t)row*FFD + t + 256];
  __syncthreads();
  float acc = b2[t] + bf2f(out4_b[(size_t)row*DM + t]);
  #pragma unroll 8
  for (int k = 0; k < FFD; k++) acc += a[k]*bf2f(W2[k*DM + t]);
  float mean = blk_sum256(acc, tmp)*(1.f/DM);
  float c = acc - mean;
  float var = blk_sum256(c*c, tmp)*(1.f/DM);
  float o = c*rsqrtf(var + 1e-5f)*g3[t] + b3[t];
  out[(size_t)row*DM + t] = o;
}

extern "C" void kernel_launch(void* const* d_in, const int* in_sizes, int n_in,
                              void* d_out, int out_size, void* d_ws, size_t ws_size,
                              hipStream_t stream) {
  const float* queries = (const float*)d_in[0];
  const float* bev     = (const float*)d_in[1];
  const float* ref     = (const float*)d_in[2];
  const float* og      = (const float*)d_in[3];
  const float* mask    = (const float*)d_in[4];
  const float* Wq = (const float*)d_in[5];  const float* bq = (const float*)d_in[6];
  const float* Wk = (const float*)d_in[7];  const float* bk = (const float*)d_in[8];
  const float* Wv = (const float*)d_in[9];  const float* bv = (const float*)d_in[10];
  const float* Wo = (const float*)d_in[11]; const float* bo = (const float*)d_in[12];
  const float* ln1g = (const float*)d_in[13]; const float* ln1b = (const float*)d_in[14];
  const float* Wval = (const float*)d_in[15]; const float* bval = (const float*)d_in[16];
  const float* Woff = (const float*)d_in[17]; const float* boff = (const float*)d_in[18];
  const float* Wattn = (const float*)d_in[19]; const float* battn = (const float*)d_in[20];
  const float* Wdo = (const float*)d_in[21]; const float* bdo = (const float*)d_in[22];
  const float* ln2g = (const float*)d_in[23]; const float* ln2b = (const float*)d_in[24];
  const float* W1 = (const float*)d_in[25]; const float* b1 = (const float*)d_in[26];
  const float* W2 = (const float*)d_in[27]; const float* b2 = (const float*)d_in[28];
  const float* ln3g = (const float*)d_in[29]; const float* ln3b = (const float*)d_in[30];

  const int M = NB*QN;            // 3600
  char* base = (char*)d_ws;
  bf16*  Wb      = (bf16*)base;                      base += 1359872;   // 679936 bf16
  bf16*  WvalT   = (bf16*)base;                      base += 131072;    // 65536 bf16 [n][k]
  bf16*  qh_b    = (bf16*)base;                      base += 1843200;
  bf16*  kh_b    = (bf16*)base;                      base += 1843200;
  bf16*  vt      = (bf16*)base;                      base += 1966080;   // [1024][960]
  bf16*  attn_b  = (bf16*)base;                      base += 1843200;
  float* out2    = (float*)base;                     base += 3686400;
  float* aug     = (float*)base;                     base += 3686400;
  float* sampled = (float*)base;                     base += 3686400;
  bf16*  out4_b  = (bf16*)base;                      base += 1843200;
  float* hid     = (float*)base;                     base += 7372800;
  float* locb    = (float*)base;                     base += 921600;
  float* awb     = (float*)base;                     base += 460800;
  bf16*  value   = (bf16*)base;                      // 81,920,000 bytes

  bf16* Wqb    = Wb;
  bf16* Wkb    = Wb + 65536;
  bf16* Wvb    = Wb + 131072;
  bf16* Wob    = Wb + 196608;
  bf16* Woffb  = Wb + 327680;
  bf16* Wattnb = Wb + 344064;
  bf16* Wdob   = Wb + 352256;
  bf16* W1b    = Wb + 417792;
  bf16* W2b    = Wb + 548864;

  cvtW_kernel<<<2656, 256, 0, stream>>>(Wq, Wk, Wv, Wo, Wval, Woff, Wattn, Wdo, W1, W2, Wb);
  cvtWvalT_kernel<<<256, 256, 0, stream>>>(Wval, WvalT);
  proj3_kernel<<<dim3(M/8, 3), 256, 0, stream>>>(queries, og, Wqb, bq, Wkb, bk, Wvb, bv, qh_b, kh_b, vt);
  mha_flash<<<dim3(29, HH, NB), 128, 0, stream>>>(qh_b, kh_b, vt, mask, attn_b);
  wo_ln_kernel<<<M, 256, 0, stream>>>(attn_b, Wob, bo, queries, og, ln1g, ln1b, out2, aug);
  value_gemm_mfma<<<(NB*NV)/64, 256, 0, stream>>>(bev, WvalT, bval, value);
  off_attn_kernel<<<M, 128, 0, stream>>>(aug, ref, Woffb, boff, Wattnb, battn, locb, awb);
  deform_kernel<<<M, 256, 0, stream>>>(value, locb, awb, sampled);
  wdo_ln_kernel<<<M, 256, 0, stream>>>(sampled, Wdob, bdo, mask, out2, ln2g, ln2b, out4_b);
  ffn1_kernel<<<M, 256, 0, stream>>>(out4_b, W1b, b1, hid);
  ffn2_ln_kernel<<<M, 256, 0, stream>>>(hid, W2b, b2, out4_b, ln3g, ln3b, (float*)d_out);
}